// Round 7
// baseline (913.477 us; speedup 1.0000x reference)
//
#include <hip/hip_runtime.h>
#include <math.h>

#define BQ 4096
#define F_SUP 5
#define MAXK 64
#define ED 128
#define DM 256
#define DI 512
#define LH 512
#define NG 2048
#define PADX 200000
#define KNB 10
#define NBTOT 8202            // 2*BQ + 2*F_SUP neighbor groups
#define MROWS 82048           // 8202*10 padded to 641*128
#define MREAL 82020
#define MQ 4224               // 4101 rows padded to 33*128
#define EMB_ELEMS 25600128    // 200001*128
#define NEMB8 3200016         // EMB_ELEMS/8
#define LSTM_BLKS 512

typedef unsigned short u16;
typedef __attribute__((ext_vector_type(8))) short short8;
typedef __attribute__((ext_vector_type(4))) float floatx4;

__device__ __forceinline__ float sigf(float x) { return 1.0f / (1.0f + __expf(-x)); }
__device__ __forceinline__ float tanh_fast(float x) {
  float a = fabsf(x);
  float e = __expf(-2.0f * a);
  float t = (1.0f - e) / (1.0f + e);
  return copysignf(t, x);
}
__device__ __forceinline__ u16 f2bf(float f) {
  unsigned u = __float_as_uint(f);
  unsigned r = (u + 0x7FFFu + ((u >> 16) & 1u)) >> 16;
  return (u16)r;
}
__device__ __forceinline__ float bf2f(u16 u) {
  return __uint_as_float(((unsigned)u) << 16);
}
__device__ __forceinline__ void gl2lds16(const void* g, void* l) {
  __builtin_amdgcn_global_load_lds(
      (const __attribute__((address_space(1))) void*)g,
      (__attribute__((address_space(3))) void*)l, 16, 0, 0);
}

// manual grid barrier: all LSTM_BLKS blocks are co-resident (512 blocks = 2/CU,
// guaranteed by __launch_bounds__(256,2): VGPR<=256, LDS 32KB; grid = 2x256 CUs).
__device__ __forceinline__ void grid_sync(int* cnt) {
  __threadfence();                                  // release our writes (agent scope)
  __syncthreads();
  if (threadIdx.x == 0) {
    __hip_atomic_fetch_add(cnt, 1, __ATOMIC_ACQ_REL, __HIP_MEMORY_SCOPE_AGENT);
    while (__hip_atomic_load(cnt, __ATOMIC_ACQUIRE, __HIP_MEMORY_SCOPE_AGENT) < LSTM_BLKS)
      __builtin_amdgcn_s_sleep(8);
  }
  __syncthreads();
  __threadfence();                                  // acquire: invalidate stale cache
}

// ============ phase 0: ALL weight casts/permutes + bf16 symbol table + zeros ============
__global__ __launch_bounds__(256) void prep_all(
    const float* __restrict__ emb, u16* __restrict__ embb,
    const float* __restrict__ p1, const float* __restrict__ p2,
    const float* __restrict__ gcnw, const float* __restrict__ wih,
    const float* __restrict__ whh, const float* __restrict__ bih,
    const float* __restrict__ bhh,
    u16* __restrict__ p1b, u16* __restrict__ p2b, u16* __restrict__ gcnb,
    u16* __restrict__ wihb, u16* __restrict__ whhb, float* __restrict__ bihh,
    float* __restrict__ outz, int* __restrict__ scnt)
{
  long gid = (long)blockIdx.x * 256 + threadIdx.x;
  if (gid < (long)NEMB8) {
    long i = gid * 8;
    float4 f0 = *(const float4*)(emb + i);
    float4 f1 = *(const float4*)(emb + i + 4);
    short8 s;
    s[0]=(short)f2bf(f0.x); s[1]=(short)f2bf(f0.y); s[2]=(short)f2bf(f0.z); s[3]=(short)f2bf(f0.w);
    s[4]=(short)f2bf(f1.x); s[5]=(short)f2bf(f1.y); s[6]=(short)f2bf(f1.z); s[7]=(short)f2bf(f1.w);
    *(short8*)(embb + i) = s;
    return;
  }
  int g2 = (int)(gid - NEMB8);
  if (g2 < 131072) { p1b[g2] = f2bf(p1[g2]); }
  else if (g2 < 262144) { int i = g2 - 131072; p2b[i] = f2bf(p2[i]); }
  else if (g2 < 294912) { int i = g2 - 262144; gcnb[i] = f2bf(gcnw[i]); }
  else if (g2 < 819200) {
    int i = g2 - 294912; int p = i >> 8, k = i & 255;
    int g = (p >> 4) & 3, uu = (p >> 7) * 32 + ((p >> 6) & 1) * 16 + (p & 15);
    int n = g * 512 + uu;
    wihb[i] = f2bf(wih[(long)n * DM + k]);
  } else if (g2 < 1343488) {
    int i = g2 - 819200; int p = i >> 8, k = i & 255;
    int g = (p >> 4) & 3, uu = (p >> 7) * 32 + ((p >> 6) & 1) * 16 + (p & 15);
    int n = g * 512 + uu;
    whhb[i] = f2bf(whh[(long)n * LH + k]);
  } else if (g2 < 1345536) {
    int p = g2 - 1343488;
    int g = (p >> 4) & 3, uu = (p >> 7) * 32 + ((p >> 6) & 1) * 16 + (p & 15);
    int n = g * 512 + uu;
    bihh[p] = bih[n] + bhh[n];
  } else if (g2 < 1345536 + BQ) {
    outz[g2 - 1345536] = 0.f;                       // final dot accumulates atomically
  } else if (g2 < 1345536 + BQ + 8) {
    scnt[g2 - 1345536 - BQ] = 0;                    // grid-sync counters
  }
}

// ============ phase A: bf16 gather + sims + fused rank/select ============
__global__ __launch_bounds__(256) void nbr_simrank_kernel(
    const int* __restrict__ query, const int* __restrict__ support,
    const int* __restrict__ q_l1, const int* __restrict__ q_r1,
    const int* __restrict__ s_l1, const int* __restrict__ s_r1,
    const u16* __restrict__ embb, int* __restrict__ idxA, int* __restrict__ meta)
{
  __shared__ float sE[128];
  __shared__ float simS[64];
  __shared__ int relS[64], entS[64];
  int tid = threadIdx.x;
  int b = blockIdx.x;
  const int* conn; int self_id;
  if (b < BQ)              { int i = b;              conn = q_l1 + (long)i*(MAXK*2); self_id = query[2*i];   }
  else if (b < 2*BQ)       { int i = b - BQ;         conn = q_r1 + (long)i*(MAXK*2); self_id = query[2*i+1]; }
  else if (b < 2*BQ+F_SUP) { int i = b - 2*BQ;       conn = s_l1 + (long)i*(MAXK*2); self_id = support[2*i]; }
  else                     { int i = b - 2*BQ-F_SUP; conn = s_r1 + (long)i*(MAXK*2); self_id = support[2*i+1]; }

  int k = tid >> 2, part = tid & 3;
  int2 rc = *(const int2*)(conn + 2 * k);           // x=rel, y=ent
  if (tid < 16) {
    short8 s = *(const short8*)(embb + (long)self_id * ED + tid * 8);
    #pragma unroll
    for (int j = 0; j < 8; ++j) sE[tid * 8 + j] = bf2f((u16)s[j]);
  }
  __syncthreads();

  const u16* er = embb + (long)rc.y * ED + part * 8;
  float dot = 0.f, sq = 0.f;
  #pragma unroll
  for (int i = 0; i < 4; ++i) {
    short8 e8 = *(const short8*)(er + i * 32);
    #pragma unroll
    for (int j = 0; j < 8; ++j) {
      float e = bf2f((u16)e8[j]);
      float s = sE[i * 32 + part * 8 + j];
      dot += e * s; sq += e * e;
    }
  }
  dot += __shfl_xor(dot, 1); dot += __shfl_xor(dot, 2);
  sq  += __shfl_xor(sq, 1);  sq  += __shfl_xor(sq, 2);
  if (part == 0) {
    float ne = fmaxf(sqrtf(sq), 1e-12f);
    float sim = dot / ne;
    if (rc.x == PADX) sim -= 1e9f;
    simS[k] = sim; relS[k] = rc.x; entS[k] = rc.y;
  }
  __syncthreads();

  if (tid < 64) {
    float my = simS[tid];
    int rank = 0;
    #pragma unroll
    for (int j = 0; j < 64; ++j) {
      float s = simS[j];                            // broadcast LDS read
      rank += ((s > my) || (s == my && j < tid)) ? 1 : 0;
    }
    bool val = (rank < KNB) && (relS[tid] != PADX);
    unsigned long long vm = __ballot(val ? 1 : 0);  // wave 0 only
    int cnt = __popcll(vm);
    long base = (long)b * 10;
    if (val) {
      int pos = __popcll(vm & ((1ull << tid) - 1ull));
      int2 p; p.x = relS[tid]; p.y = entS[tid];
      *(int2*)(idxA + (base + pos) * 2) = p;
    }
    if (tid >= cnt && tid < KNB) {
      int2 pp; pp.x = PADX; pp.y = PADX;            // PAD row of emb is all zeros
      *(int2*)(idxA + (base + tid) * 2) = pp;
    }
    if (tid == 0) meta[b] = cnt;
  }
  if (b == 0 && tid >= 64 && tid < 64 + 2 * (MROWS - MREAL)) {
    idxA[(long)MREAL * 2 + (tid - 64)] = PADX;      // pad rows -> zero emb row
  }
}

// ============ proj GEMM with fused gather: proj[M,128] = emb_bf16[idx] @ gcn_w^T ============
__global__ __launch_bounds__(256) void proj_gather_gemm(
    const int* __restrict__ idxA, const u16* __restrict__ embb,
    const u16* __restrict__ W, u16* __restrict__ proj)
{
  __shared__ u16 As[128 * 32];
  __shared__ u16 Bs[128 * 32];
  __shared__ int idxS[256];
  int tid = threadIdx.x;
  int bm = blockIdx.x;
  idxS[tid] = idxA[bm * 256 + tid];
  int lane = tid & 63, wave = tid >> 6;
  int wm = (wave & 1) * 64, wn = (wave >> 1) * 64;
  int col = lane & 15, quad = lane >> 4;

  floatx4 acc[4][4];
  #pragma unroll
  for (int i = 0; i < 4; ++i)
    #pragma unroll
    for (int j = 0; j < 4; ++j) { floatx4 z = {0.f,0.f,0.f,0.f}; acc[i][j] = z; }
  __syncthreads();

  for (int k0 = 0; k0 < 256; k0 += 32) {
    int half = k0 >> 7, koff = k0 & 127;
    #pragma unroll
    for (int t = 0; t < 2; ++t) {
      int c = t * 256 + tid;
      int rb = c >> 2, o = c & 3;
      int og = o ^ (rb & 3);
      gl2lds16(W + (long)rb * 256 + k0 + og * 8, &Bs[(size_t)c * 8]);
      int id = idxS[rb * 2 + half];
      gl2lds16(embb + (long)id * ED + koff + og * 8, &As[(size_t)c * 8]);
    }
    __syncthreads();
    short8 af[4], bfr[4];
    #pragma unroll
    for (int i = 0; i < 4; ++i) {
      int ra = wm + i * 16 + col;
      af[i] = *(const short8*)&As[(size_t)(ra * 4 + (quad ^ (ra & 3))) * 8];
      int rb = wn + i * 16 + col;
      bfr[i] = *(const short8*)&Bs[(size_t)(rb * 4 + (quad ^ (rb & 3))) * 8];
    }
    #pragma unroll
    for (int i = 0; i < 4; ++i)
      #pragma unroll
      for (int j = 0; j < 4; ++j)
        acc[i][j] = __builtin_amdgcn_mfma_f32_16x16x32_bf16(af[i], bfr[j], acc[i][j], 0, 0, 0);
    __syncthreads();
  }
  int gm0 = bm * 128 + wm + quad * 4;
  int gn0 = wn + col;
  #pragma unroll
  for (int i = 0; i < 4; ++i)
    #pragma unroll
    for (int j = 0; j < 4; ++j)
      #pragma unroll
      for (int rr = 0; rr < 4; ++rr)
        proj[(long)(gm0 + i * 16 + rr) * 128 + gn0 + j * 16] = f2bf(acc[i][j][rr]);
}

// ============ phase C: leaky/sum + gate MLP + tanh output ============
__global__ __launch_bounds__(128) void nbr_post_kernel(
    const int* __restrict__ query, const int* __restrict__ support,
    const int* __restrict__ q_deg_l, const int* __restrict__ q_deg_r,
    const int* __restrict__ s_deg_l, const int* __restrict__ s_deg_r,
    const float* __restrict__ emb,
    const u16* __restrict__ proj, const int* __restrict__ meta,
    const float* __restrict__ gcn_w_b, const float* __restrict__ gcn_b,
    const float* __restrict__ g1_w, const float* __restrict__ g1_b,
    const float* __restrict__ ln1_g, const float* __restrict__ ln1_b,
    const float* __restrict__ g2_w, const float* __restrict__ g2_b,
    const float* __restrict__ gate_temp,
    float* __restrict__ qv, u16* __restrict__ qv_bf)
{
  __shared__ __align__(16) float aggS[128];
  __shared__ float sEs[128];
  __shared__ float gateS;
  int tid = threadIdx.x, b = blockIdx.x;
  int deg, self_id, row, colb;
  if (b < BQ)              { int i = b;              deg = q_deg_l[i]; self_id = query[2*i];     row = i;        colb = 0;  }
  else if (b < 2*BQ)       { int i = b - BQ;         deg = q_deg_r[i]; self_id = query[2*i+1];   row = i;        colb = ED; }
  else if (b < 2*BQ+F_SUP) { int i = b - 2*BQ;       deg = s_deg_l[i]; self_id = support[2*i];   row = BQ + i;   colb = 0;  }
  else                     { int i = b - 2*BQ-F_SUP; deg = s_deg_r[i]; self_id = support[2*i+1]; row = BQ + i;   colb = ED; }
  float* outp = qv + (long)row * DM + colb;
  u16*  outpb = qv_bf + (long)row * DM + colb;

  int cnt = meta[b];
  float denom = fmaxf((float)cnt, 1.0f);
  float bsum = gcn_w_b[tid] + gcn_b[tid];
  float agg = 0.f;
  long pbase = (long)b * 10;
  for (int kk = 0; kk < cnt; ++kk) {
    float z = bf2f(proj[(pbase + kk) * 128 + tid]) + bsum;
    z = (z >= 0.f) ? z : 0.01f * z;
    agg += z;
  }
  agg /= denom;
  aggS[tid] = agg;
  sEs[tid] = emb[(long)self_id * ED + tid];
  __syncthreads();

  if (tid < 64) {
    int e = tid;
    const float4* g1r = (const float4*)(g1_w + e * ED);
    float y = g1_b[e];
    #pragma unroll 8
    for (int j = 0; j < 32; ++j) {
      float4 w = g1r[j];
      float4 a = *(const float4*)&aggS[j * 4];
      y += w.x*a.x + w.y*a.y + w.z*a.z + w.w*a.w;
    }
    float s = y;
    #pragma unroll
    for (int off = 1; off < 64; off <<= 1) s += __shfl_xor(s, off);
    float mean = s * (1.0f / 64.0f);
    float dv = y - mean;
    float s2 = dv * dv;
    #pragma unroll
    for (int off = 1; off < 64; off <<= 1) s2 += __shfl_xor(s2, off);
    float var = s2 * (1.0f / 64.0f);
    float hv = dv / sqrtf(var + 1e-5f) * ln1_g[e] + ln1_b[e];
    hv = fmaxf(hv, 0.f);
    float lp = hv * g2_w[e];
    #pragma unroll
    for (int off = 1; off < 64; off <<= 1) lp += __shfl_xor(lp, off);
    if (e == 0) {
      float logit = lp + g2_b[0];
      float temp = fminf(fmaxf(gate_temp[0], 0.1f), 5.0f);
      float gate = 1.0f / (1.0f + expf(-logit / temp));
      if (deg <= 0) gate = 0.f;
      gateS = gate;
    }
  }
  __syncthreads();
  float o = tanhf(sEs[tid] + gateS * aggS[tid]);
  outp[tid] = o;
  outpb[tid] = f2bf(o);
}

// ============ 64x64-tile MFMA GEMM (encoder): C = A @ W^T (+bias, relu) ============
__global__ __launch_bounds__(256) void gemm64(
    const u16* __restrict__ A, int lda,
    const u16* __restrict__ W, int ldw,
    int N, int K,
    float* __restrict__ Cout, u16* __restrict__ Cbf,
    const float* __restrict__ bias0, int relu)
{
  __shared__ u16 As[64 * 32];
  __shared__ u16 Bs[64 * 32];
  int tid = threadIdx.x;
  int nb = N >> 6;
  int bn = blockIdx.x % nb, bm = blockIdx.x / nb;
  int lane = tid & 63, wave = tid >> 6;
  int wm = (wave & 1) * 32, wn = (wave >> 1) * 32;
  int col = lane & 15, quad = lane >> 4;

  floatx4 acc[2][2];
  #pragma unroll
  for (int i = 0; i < 2; ++i)
    #pragma unroll
    for (int j = 0; j < 2; ++j) { floatx4 z = {0.f,0.f,0.f,0.f}; acc[i][j] = z; }

  for (int k0 = 0; k0 < K; k0 += 32) {
    {
      int r = tid >> 2, o = tid & 3;
      int og = o ^ (r & 3);
      gl2lds16(A + (long)(bm * 64 + r) * lda + k0 + og * 8, &As[(size_t)tid * 8]);
      gl2lds16(W + (long)(bn * 64 + r) * ldw + k0 + og * 8, &Bs[(size_t)tid * 8]);
    }
    __syncthreads();
    short8 af[2], bfr[2];
    #pragma unroll
    for (int i = 0; i < 2; ++i) {
      int ra = wm + i * 16 + col;
      af[i] = *(const short8*)&As[(size_t)(ra * 4 + (quad ^ (ra & 3))) * 8];
      int rb = wn + i * 16 + col;
      bfr[i] = *(const short8*)&Bs[(size_t)(rb * 4 + (quad ^ (rb & 3))) * 8];
    }
    #pragma unroll
    for (int i = 0; i < 2; ++i)
      #pragma unroll
      for (int j = 0; j < 2; ++j)
        acc[i][j] = __builtin_amdgcn_mfma_f32_16x16x32_bf16(af[i], bfr[j], acc[i][j], 0, 0, 0);
    __syncthreads();
  }

  int gm0 = bm * 64 + wm + quad * 4;
  int gn0 = bn * 64 + wn + col;
  #pragma unroll
  for (int i = 0; i < 2; ++i) {
    #pragma unroll
    for (int j = 0; j < 2; ++j) {
      int n = gn0 + j * 16;
      float bv = bias0 ? bias0[n] : 0.f;
      #pragma unroll
      for (int rr = 0; rr < 4; ++rr) {
        int m = gm0 + i * 16 + rr;
        float v = acc[i][j][rr] + bv;
        if (relu) v = fmaxf(v, 0.f);
        if (Cout) Cout[(long)m * N + n] = v;
        if (Cbf)  Cbf[(long)m * N + n] = f2bf(v);
      }
    }
  }
}

// ============ residual layernorm -> qe (fp32 + bf16), rows 0..4100 ============
__global__ __launch_bounds__(256) void ln_residual_kernel(
    const float* __restrict__ h2buf, const float* __restrict__ xbuf,
    const float* __restrict__ lng, const float* __restrict__ lnb,
    float* __restrict__ out, u16* __restrict__ outb)
{
  __shared__ float red[4];
  int r = blockIdx.x, tid = threadIdx.x;
  float v = h2buf[(long)r * DM + tid] + xbuf[(long)r * DM + tid];
  float s = v;
  #pragma unroll
  for (int off = 1; off < 64; off <<= 1) s += __shfl_xor(s, off);
  if ((tid & 63) == 0) red[tid >> 6] = s;
  __syncthreads();
  float mean = (red[0] + red[1] + red[2] + red[3]) * (1.0f / 256.0f);
  __syncthreads();
  float dv = v - mean;
  float s2 = dv * dv;
  #pragma unroll
  for (int off = 1; off < 64; off <<= 1) s2 += __shfl_xor(s2, off);
  if ((tid & 63) == 0) red[tid >> 6] = s2;
  __syncthreads();
  float var = (red[0] + red[1] + red[2] + red[3]) * (1.0f / 256.0f);
  float o = dv / sqrtf(var + 1e-5f) * lng[tid] + lnb[tid];
  out[(long)r * DM + tid] = o;
  outb[(long)r * DM + tid] = f2bf(o);
}

// 128x128 K=256 GEMM inner loop (shared by all LSTM phases)
__device__ __forceinline__ void kloop128(
    const u16* __restrict__ A, const u16* __restrict__ W,
    u16* As, u16* Bs, int bm, int bn, int tid,
    int wm, int wn, int col, int quad, floatx4 (&acc)[4][4])
{
  for (int k0 = 0; k0 < 256; k0 += 32) {
    #pragma unroll
    for (int t = 0; t < 2; ++t) {
      int c = t * 256 + tid;
      int r = c >> 2, o = c & 3;
      int og = o ^ (r & 3);
      gl2lds16(A + (long)(bm * 128 + r) * 256 + k0 + og * 8, &As[(size_t)c * 8]);
      gl2lds16(W + (long)(bn * 128 + r) * 256 + k0 + og * 8, &Bs[(size_t)c * 8]);
    }
    __syncthreads();
    short8 af[4], bfr[4];
    #pragma unroll
    for (int i = 0; i < 4; ++i) {
      int ra = wm + i * 16 + col;
      af[i] = *(const short8*)&As[(size_t)(ra * 4 + (quad ^ (ra & 3))) * 8];
      int rb = wn + i * 16 + col;
      bfr[i] = *(const short8*)&Bs[(size_t)(rb * 4 + (quad ^ (rb & 3))) * 8];
    }
    #pragma unroll
    for (int i = 0; i < 4; ++i)
      #pragma unroll
      for (int j = 0; j < 4; ++j)
        acc[i][j] = __builtin_amdgcn_mfma_f32_16x16x32_bf16(af[i], bfr[j], acc[i][j], 0, 0, 0);
    __syncthreads();
  }
}

// ============ fused LSTM chain: rider (sg+s_corr) + 4 steps + final dot, ONE kernel ============
// 512 blocks (bm 0..31 x bn 0..15), all co-resident (launch_bounds(256,2) => 2 blocks/CU),
// manual grid barriers between steps. c-state and bf16-rounded gq live in REGISTERS across
// steps 2..3 (fb is thread-invariant); gq_fr/cstate written once for phase 4's remapped read.
// Phase 4 re-tiles to 64-row blocks (bn4=blk&7, bm4=blk>>3): u<256 only, fused dot->atomics.
__global__ __launch_bounds__(256, 2) void lstm_all(
    const u16* __restrict__ qe_bf, const u16* __restrict__ wihb,
    const u16* __restrict__ whhb, const float* __restrict__ bihh,
    const float* __restrict__ qe, const float* __restrict__ whh_f,
    u16* __restrict__ gq_fr, float* __restrict__ cstate,
    u16* __restrict__ hbf0, u16* __restrict__ hbf1,
    float* __restrict__ sg, float* __restrict__ s_corr,
    float* __restrict__ dotv, int* __restrict__ scnt)
{
  __shared__ u16 As[128 * 32];
  __shared__ u16 Bs[128 * 32];
  int tid = threadIdx.x;
  int blk = blockIdx.x;
  int lane = tid & 63, wave = tid >> 6;
  int col = lane & 15, quad = lane >> 4;

  // ---- phase 0: sg + permuted s_corr (block handles rows blk*4..blk*4+3) ----
  {
    float* sgS = (float*)As;
    float v = 0.f;
    #pragma unroll
    for (int r = 0; r < F_SUP; ++r) v += qe[(long)(BQ + r) * DM + tid];
    v *= (1.0f / (float)F_SUP);
    sgS[tid] = v;
    if (blk == 0) sg[tid] = v;
    __syncthreads();
    int n = blk * 4 + wave;                         // orig row 0..2047
    float4 w = *(const float4*)(whh_f + (long)n * LH + DM + lane * 4);
    float4 s = *(const float4*)&sgS[lane * 4];
    float d = w.x*s.x + w.y*s.y + w.z*s.z + w.w*s.w;
    #pragma unroll
    for (int off = 1; off < 64; off <<= 1) d += __shfl_xor(d, off);
    if (lane == 0) {
      int g = n >> 9, uu = n & 511;
      int p = (uu >> 5) * 128 + ((uu >> 4) & 1) * 64 + g * 16 + (uu & 15);
      s_corr[p] = d;
    }
    __syncthreads();                                // done with sgS (As reused below)
  }

  int bn = blk & 15, bm = blk >> 4;
  int wm = (wave & 1) * 64, wn = (wave >> 1) * 64;
  int u = bn * 32 + (wave >> 1) * 16 + col;
  long fb = ((long)blk * 4 + wave) * 64 + lane;

  float qev[16];
  if (u < DM) {
    #pragma unroll
    for (int i = 0; i < 4; ++i)
      #pragma unroll
      for (int r = 0; r < 4; ++r) {
        int m = bm * 128 + (wave & 1) * 64 + i * 16 + quad * 4 + r;
        qev[i * 4 + r] = qe[(long)m * DM + u];
      }
  }

  u16 gqa[64];                                      // bf16-rounded step-1 gates (reg-resident)
  float cc[16];                                     // c-state (reg-resident, steps 1..3)

  // ---- phase 1: step 1 (c=0), gq -> regs + global (for phase 4) ----
  {
    float scv[4];
    #pragma unroll
    for (int j = 0; j < 4; ++j)
      scv[j] = bihh[bn * 128 + (wave >> 1) * 64 + j * 16 + col];
    floatx4 acc[4][4];
    #pragma unroll
    for (int i = 0; i < 4; ++i)
      #pragma unroll
      for (int j = 0; j < 4; ++j) { floatx4 z = {0.f,0.f,0.f,0.f}; acc[i][j] = z; }
    kloop128(qe_bf, wihb, As, Bs, bm, bn, tid, wm, wn, col, quad, acc);
    #pragma unroll
    for (int i = 0; i < 4; ++i)
      #pragma unroll
      for (int j = 0; j < 4; ++j)
        #pragma unroll
        for (int r = 0; r < 4; ++r)
          gqa[(i * 4 + j) * 4 + r] = f2bf(acc[i][j][r] + scv[j]);
    short8* gp = (short8*)(gq_fr + fb * 64);
    #pragma unroll
    for (int t = 0; t < 8; ++t) gp[t] = *(short8*)&gqa[t * 8];
    #pragma unroll
    for (int i = 0; i < 4; ++i)
      #pragma unroll
      for (int r = 0; r < 4; ++r) {
        float gI = acc[i][0][r] + scv[0];
        float gG = acc[i][2][r] + scv[2];
        float gO = acc[i][3][r] + scv[3];
        float cn = sigf(gI) * tanh_fast(gG);        // c_prev = 0
        cc[i * 4 + r] = cn;
        if (u < DM) {
          int m = bm * 128 + (wave & 1) * 64 + i * 16 + quad * 4 + r;
          hbf0[(long)m * DM + u] = f2bf(qev[i * 4 + r] + sigf(gO) * tanh_fast(cn));
        }
      }
  }
  grid_sync(&scnt[0]);

  float scv2[4];
  #pragma unroll
  for (int j = 0; j < 4; ++j)
    scv2[j] = s_corr[bn * 128 + (wave >> 1) * 64 + j * 16 + col];

  // ---- phases 2,3: steps 2..3 (h ping-pong; c,gq stay in regs) ----
  #pragma unroll 1
  for (int step = 0; step < 2; ++step) {
    const u16* Ain = step ? hbf1 : hbf0;
    u16* hout = step ? hbf0 : hbf1;
    floatx4 acc[4][4];
    #pragma unroll
    for (int i = 0; i < 4; ++i)
      #pragma unroll
      for (int j = 0; j < 4; ++j) { floatx4 z = {0.f,0.f,0.f,0.f}; acc[i][j] = z; }
    kloop128(Ain, whhb, As, Bs, bm, bn, tid, wm, wn, col, quad, acc);
    #pragma unroll
    for (int i = 0; i < 4; ++i)
      #pragma unroll
      for (int r = 0; r < 4; ++r) {
        float gI = acc[i][0][r] + scv2[0] + bf2f(gqa[(i * 4 + 0) * 4 + r]);
        float gF = acc[i][1][r] + scv2[1] + bf2f(gqa[(i * 4 + 1) * 4 + r]);
        float gG = acc[i][2][r] + scv2[2] + bf2f(gqa[(i * 4 + 2) * 4 + r]);
        float gO = acc[i][3][r] + scv2[3] + bf2f(gqa[(i * 4 + 3) * 4 + r]);
        float cn = sigf(gF) * cc[i * 4 + r] + sigf(gI) * tanh_fast(gG);
        cc[i * 4 + r] = cn;
        if (u < DM) {
          int m = bm * 128 + (wave & 1) * 64 + i * 16 + quad * 4 + r;
          hout[(long)m * DM + u] = f2bf(qev[i * 4 + r] + sigf(gO) * tanh_fast(cn));
        }
      }
    if (step == 1) {                                // cstate needed by phase 4 remap
      float4* cp = (float4*)(cstate + fb * 16);
      #pragma unroll
      for (int t = 0; t < 4; ++t) cp[t] = *(float4*)&cc[t * 4];
    }
    grid_sync(&scnt[1 + step]);
  }

  // ---- phase 4: step 4 + fused final dot (64-row re-tile: all 512 blocks active) ----
  {
    int bn4 = blk & 7, bm4 = blk >> 3;
    int w1 = wave & 1, w2 = wave >> 1;
    int u4 = bn4 * 32 + w2 * 16 + col;
    long fb4 = (((long)(bm4 >> 1) * 16 + bn4) * 4 + ((bm4 & 1) | (w2 << 1))) * 64 + lane;
    float scv4[4], qev4[8], cpv4[8]; u16 gqa4[32];
    #pragma unroll
    for (int j = 0; j < 4; ++j)
      scv4[j] = s_corr[bn4 * 128 + w2 * 64 + j * 16 + col];
    {
      const short8* gp = (const short8*)(gq_fr + fb4 * 64);
      const float4* cp = (const float4*)(cstate + fb4 * 16);
      #pragma unroll
      for (int i = 0; i < 2; ++i) {
        int io = w1 * 2 + i;
        *(short8*)&gqa4[i * 16]     = gp[io * 2];
        *(short8*)&gqa4[i * 16 + 8] = gp[io * 2 + 1];
        *(float4*)&cpv4[i * 4]      = cp[io];
      }
      #pragma unroll
      for (int i = 0; i < 2; ++i)
        #pragma unroll
        for (int r = 0; r < 4; ++r) {
          int m = bm4 * 64 + w1 * 32 + i * 16 + quad * 4 + r;
          qev4[i * 4 + r] = qe[(long)m * DM + u4];
        }
    }
    float sgu = sg[u4];

    floatx4 acc[2][4];
    #pragma unroll
    for (int i = 0; i < 2; ++i)
      #pragma unroll
      for (int j = 0; j < 4; ++j) { floatx4 z = {0.f,0.f,0.f,0.f}; acc[i][j] = z; }

    for (int k0 = 0; k0 < 256; k0 += 32) {
      {
        int r = tid >> 2, o = tid & 3;
        int og = o ^ (r & 3);
        gl2lds16(hbf0 + (long)(bm4 * 64 + r) * DM + k0 + og * 8, &As[(size_t)tid * 8]);
      }
      #pragma unroll
      for (int t = 0; t < 2; ++t) {
        int c = t * 256 + tid;
        int r = c >> 2, o = c & 3;
        int og = o ^ (r & 3);
        gl2lds16(whhb + (long)(bn4 * 128 + r) * DM + k0 + og * 8, &Bs[(size_t)c * 8]);
      }
      __syncthreads();
      short8 af[2], bfr[4];
      #pragma unroll
      for (int i = 0; i < 2; ++i) {
        int ra = w1 * 32 + i * 16 + col;
        af[i] = *(const short8*)&As[(size_t)(ra * 4 + (quad ^ (ra & 3))) * 8];
      }
      #pragma unroll
      for (int j = 0; j < 4; ++j) {
        int rb = w2 * 64 + j * 16 + col;
        bfr[j] = *(const short8*)&Bs[(size_t)(rb * 4 + (quad ^ (rb & 3))) * 8];
      }
      #pragma unroll
      for (int i = 0; i < 2; ++i)
        #pragma unroll
        for (int j = 0; j < 4; ++j)
          acc[i][j] = __builtin_amdgcn_mfma_f32_16x16x32_bf16(af[i], bfr[j], acc[i][j], 0, 0, 0);
      __syncthreads();
    }

    #pragma unroll
    for (int i = 0; i < 2; ++i) {
      #pragma unroll
      for (int r = 0; r < 4; ++r) {
        float gI = acc[i][0][r] + scv4[0] + bf2f(gqa4[i * 16 + 0 * 4 + r]);
        float gF = acc[i][1][r] + scv4[1] + bf2f(gqa4[i * 16 + 1 * 4 + r]);
        float gG = acc[i][2][r] + scv4[2] + bf2f(gqa4[i * 16 + 2 * 4 + r]);
        float gO = acc[i][3][r] + scv4[3] + bf2f(gqa4[i * 16 + 3 * 4 + r]);
        float cn = sigf(gF) * cpv4[i * 4 + r] + sigf(gI) * tanh_fast(gG);
        float hv = qev4[i * 4 + r] + sigf(gO) * tanh_fast(cn);
        float p = hv * sgu;
        p += __shfl_xor(p, 1); p += __shfl_xor(p, 2);
        p += __shfl_xor(p, 4); p += __shfl_xor(p, 8);
        if (col == 0) {
          int m = bm4 * 64 + w1 * 32 + i * 16 + quad * 4 + r;
          atomicAdd(&dotv[m], p);
        }
      }
    }
  }
}

extern "C" void kernel_launch(void* const* d_in, const int* in_sizes, int n_in,
                              void* d_out, int out_size, void* d_ws, size_t ws_size,
                              hipStream_t stream)
{
  const int*   query    = (const int*)  d_in[0];
  const int*   support  = (const int*)  d_in[1];
  const int*   q_l1     = (const int*)  d_in[2];
  const int*   q_deg_l  = (const int*)  d_in[3];
  const int*   q_r1     = (const int*)  d_in[4];
  const int*   q_deg_r  = (const int*)  d_in[5];
  const int*   s_l1     = (const int*)  d_in[6];
  const int*   s_deg_l  = (const int*)  d_in[7];
  const int*   s_r1     = (const int*)  d_in[8];
  const int*   s_deg_r  = (const int*)  d_in[9];
  const float* symbol_emb = (const float*)d_in[10];
  const float* gcn_w_w  = (const float*)d_in[11];
  const float* gcn_w_b  = (const float*)d_in[12];
  const float* gcn_b    = (const float*)d_in[13];
  const float* g1_w     = (const float*)d_in[14];
  const float* g1_b     = (const float*)d_in[15];
  const float* ln1_g    = (const float*)d_in[16];
  const float* ln1_b    = (const float*)d_in[17];
  const float* g2_w     = (const float*)d_in[18];
  const float* g2_b     = (const float*)d_in[19];
  const float* gate_temp= (const float*)d_in[20];
  const float* se_p1_w  = (const float*)d_in[21];
  const float* se_p1_b  = (const float*)d_in[22];
  const float* se_p2_w  = (const float*)d_in[23];
  const float* se_p2_b  = (const float*)d_in[24];
  const float* se_ln_g  = (const float*)d_in[25];
  const float* se_ln_b  = (const float*)d_in[26];
  const float* w_ih     = (const float*)d_in[27];
  const float* w_hh     = (const float*)d_in[28];
  const float* b_ih     = (const float*)d_in[29];
  const float* b_hh     = (const float*)d_in[30];

  float* ws = (float*)d_ws;
  size_t off = 0;
  float* projF   = ws + off; off += (size_t)MROWS * 128 / 2;      // bf16 proj
  float* idxF    = ws + off; off += (size_t)MROWS * 2;
  float* qv      = ws + off; off += (size_t)MQ * DM;
  float* qe      = ws + off; off += (size_t)MQ * DM;
  float* qv_bfF  = ws + off; off += (size_t)MQ * DM / 2;
  float* qe_bfF  = ws + off; off += (size_t)MQ * DM / 2;
  float* h1bF    = ws + off; off += (size_t)MQ * DI / 2;
  float* H2      = ws + off; off += (size_t)MQ * DM;
  float* gqbF    = ws + off; off += (size_t)BQ * NG / 2;          // fragment-order gates (bf16)
  float* cstate  = ws + off; off += (size_t)BQ * LH;              // fragment-order c (fp32)
  float* hbf0F   = ws + off; off += (size_t)BQ * DM / 2;
  float* hbf1F   = ws + off; off += (size_t)BQ * DM / 2;
  float* p1bF    = ws + off; off += 131072 / 2;
  float* p2bF    = ws + off; off += 131072 / 2;
  float* gcnbF   = ws + off; off += 32768 / 2;
  float* wihbF   = ws + off; off += 524288 / 2;
  float* whhbF   = ws + off; off += 524288 / 2;
  float* bihh    = ws + off; off += 2048;
  float* sg      = ws + off; off += 256;
  float* s_corr  = ws + off; off += 2048;
  float* metaF   = ws + off; off += 8448;
  float* scntF   = ws + off; off += 8;                            // grid-sync counters
  float* embbF   = ws + off; off += (size_t)EMB_ELEMS / 2;        // bf16 symbol table (51 MB)

  u16* proj   = (u16*)projF;
  int* idxA   = (int*)idxF;
  u16* qv_bf  = (u16*)qv_bfF;
  u16* qe_bf  = (u16*)qe_bfF;
  u16* H1_bf  = (u16*)h1bF;
  u16* gq_fr  = (u16*)gqbF;
  u16* hbf0   = (u16*)hbf0F;
  u16* hbf1   = (u16*)hbf1F;
  u16* p1b    = (u16*)p1bF;
  u16* p2b    = (u16*)p2bF;
  u16* gcnb   = (u16*)gcnbF;
  u16* wihb   = (u16*)wihbF;
  u16* whhb   = (u16*)whhbF;
  int* meta   = (int*)metaF;
  int* scnt   = (int*)scntF;
  u16* embb   = (u16*)embbF;

  // 0. all casts/permutes + bf16 symbol table + d_out/counter zero (one launch)
  {
    long total = (long)NEMB8 + 1345536 + BQ + 8;
    int blocks = (int)((total + 255) / 256);
    prep_all<<<blocks, 256, 0, stream>>>(symbol_emb, embb,
        se_p1_w, se_p2_w, gcn_w_w, w_ih, w_hh, b_ih, b_hh,
        p1b, p2b, gcnb, wihb, whhb, bihh, (float*)d_out, scnt);
  }

  // 1. bf16 gather + sims + fused rank/select -> idxA/meta
  nbr_simrank_kernel<<<NBTOT, 256, 0, stream>>>(
      query, support, q_l1, q_r1, s_l1, s_r1, embb, idxA, meta);

  // 2. proj = emb_bf16[idx] @ gcn_w^T   (M=82048, N=128, K=256), gather via global_load_lds
  proj_gather_gemm<<<MROWS / 128, 256, 0, stream>>>(idxA, embb, gcnb, proj);

  // 3. leaky/sum + gate MLP + tanh -> qv rows 0..4100 (query + support)
  nbr_post_kernel<<<NBTOT, 128, 0, stream>>>(
      query, support, q_deg_l, q_deg_r, s_deg_l, s_deg_r, symbol_emb,
      proj, meta, gcn_w_b, gcn_b, g1_w, g1_b, ln1_g, ln1_b, g2_w, g2_b, gate_temp,
      qv, qv_bf);

  // 4. encoder (query + 5 support rows ride along) -- 64x64 tiles for occupancy
  gemm64<<<(MQ / 64) * (DI / 64), 256, 0, stream>>>(qv_bf, 256, p1b, 256, DI, 256,
      nullptr, H1_bf, se_p1_b, 1);
  gemm64<<<(MQ / 64) * (DM / 64), 256, 0, stream>>>(H1_bf, 512, p2b, 512, DM, 512,
      H2, nullptr, se_p2_b, 0);
  ln_residual_kernel<<<BQ + F_SUP, 256, 0, stream>>>(H2, qv, se_ln_g, se_ln_b, qe, qe_bf);

  // 5. fused LSTM chain: rider + steps 1..4 + final dot, one kernel, manual grid barriers
  lstm_all<<<LSTM_BLKS, 256, 0, stream>>>(qe_bf, wihb, whhb, bihh, qe, w_hh,
      gq_fr, cstate, hbf0, hbf1, sg, s_corr, (float*)d_out, scnt);
}

// Round 8
// 383.510 us; speedup vs baseline: 2.3819x; 2.3819x over previous
//
#include <hip/hip_runtime.h>
#include <math.h>

#define BQ 4096
#define F_SUP 5
#define MAXK 64
#define ED 128
#define DM 256
#define DI 512
#define LH 512
#define NG 2048
#define PADX 200000
#define KNB 10
#define NBTOT 8202            // 2*BQ + 2*F_SUP neighbor groups
#define MROWS 82048           // 8202*10 padded to 641*128
#define MREAL 82020
#define MQ 4224               // 4101 rows padded to 33*128
#define EMB_ELEMS 25600128    // 200001*128
#define NEMB8 3200016         // EMB_ELEMS/8

typedef unsigned short u16;
typedef __attribute__((ext_vector_type(8))) short short8;
typedef __attribute__((ext_vector_type(4))) float floatx4;

__device__ __forceinline__ float sigf(float x) { return 1.0f / (1.0f + __expf(-x)); }
__device__ __forceinline__ float tanh_fast(float x) {
  float a = fabsf(x);
  float e = __expf(-2.0f * a);
  float t = (1.0f - e) / (1.0f + e);
  return copysignf(t, x);
}
__device__ __forceinline__ u16 f2bf(float f) {
  unsigned u = __float_as_uint(f);
  unsigned r = (u + 0x7FFFu + ((u >> 16) & 1u)) >> 16;
  return (u16)r;
}
__device__ __forceinline__ float bf2f(u16 u) {
  return __uint_as_float(((unsigned)u) << 16);
}
__device__ __forceinline__ void gl2lds16(const void* g, void* l) {
  __builtin_amdgcn_global_load_lds(
      (const __attribute__((address_space(1))) void*)g,
      (__attribute__((address_space(3))) void*)l, 16, 0, 0);
}

// ============ phase 0: ALL weight casts/permutes + bf16 symbol table + d_out zero ============
__global__ __launch_bounds__(256) void prep_all(
    const float* __restrict__ emb, u16* __restrict__ embb,
    const float* __restrict__ p1, const float* __restrict__ p2,
    const float* __restrict__ gcnw, const float* __restrict__ wih,
    const float* __restrict__ whh, const float* __restrict__ bih,
    const float* __restrict__ bhh,
    u16* __restrict__ p1b, u16* __restrict__ p2b, u16* __restrict__ gcnb,
    u16* __restrict__ wihb, u16* __restrict__ whhb, float* __restrict__ bihh,
    float* __restrict__ outz)
{
  long gid = (long)blockIdx.x * 256 + threadIdx.x;
  if (gid < (long)NEMB8) {
    long i = gid * 8;
    float4 f0 = *(const float4*)(emb + i);
    float4 f1 = *(const float4*)(emb + i + 4);
    short8 s;
    s[0]=(short)f2bf(f0.x); s[1]=(short)f2bf(f0.y); s[2]=(short)f2bf(f0.z); s[3]=(short)f2bf(f0.w);
    s[4]=(short)f2bf(f1.x); s[5]=(short)f2bf(f1.y); s[6]=(short)f2bf(f1.z); s[7]=(short)f2bf(f1.w);
    *(short8*)(embb + i) = s;
    return;
  }
  int g2 = (int)(gid - NEMB8);
  if (g2 < 131072) { p1b[g2] = f2bf(p1[g2]); }
  else if (g2 < 262144) { int i = g2 - 131072; p2b[i] = f2bf(p2[i]); }
  else if (g2 < 294912) { int i = g2 - 262144; gcnb[i] = f2bf(gcnw[i]); }
  else if (g2 < 819200) {
    int i = g2 - 294912; int p = i >> 8, k = i & 255;
    int g = (p >> 4) & 3, uu = (p >> 7) * 32 + ((p >> 6) & 1) * 16 + (p & 15);
    int n = g * 512 + uu;
    wihb[i] = f2bf(wih[(long)n * DM + k]);
  } else if (g2 < 1343488) {
    int i = g2 - 819200; int p = i >> 8, k = i & 255;
    int g = (p >> 4) & 3, uu = (p >> 7) * 32 + ((p >> 6) & 1) * 16 + (p & 15);
    int n = g * 512 + uu;
    whhb[i] = f2bf(whh[(long)n * LH + k]);
  } else if (g2 < 1345536) {
    int p = g2 - 1343488;
    int g = (p >> 4) & 3, uu = (p >> 7) * 32 + ((p >> 6) & 1) * 16 + (p & 15);
    int n = g * 512 + uu;
    bihh[p] = bih[n] + bhh[n];
  } else if (g2 < 1345536 + BQ) {
    outz[g2 - 1345536] = 0.f;                       // final dot accumulates atomically
  }
}

// ============ phase A: bf16 gather + sims + fused rank/select ============
__global__ __launch_bounds__(256) void nbr_simrank_kernel(
    const int* __restrict__ query, const int* __restrict__ support,
    const int* __restrict__ q_l1, const int* __restrict__ q_r1,
    const int* __restrict__ s_l1, const int* __restrict__ s_r1,
    const u16* __restrict__ embb, int* __restrict__ idxA, int* __restrict__ meta)
{
  __shared__ float sE[128];
  __shared__ float simS[64];
  __shared__ int relS[64], entS[64];
  int tid = threadIdx.x;
  int b = blockIdx.x;
  const int* conn; int self_id;
  if (b < BQ)              { int i = b;              conn = q_l1 + (long)i*(MAXK*2); self_id = query[2*i];   }
  else if (b < 2*BQ)       { int i = b - BQ;         conn = q_r1 + (long)i*(MAXK*2); self_id = query[2*i+1]; }
  else if (b < 2*BQ+F_SUP) { int i = b - 2*BQ;       conn = s_l1 + (long)i*(MAXK*2); self_id = support[2*i]; }
  else                     { int i = b - 2*BQ-F_SUP; conn = s_r1 + (long)i*(MAXK*2); self_id = support[2*i+1]; }

  int k = tid >> 2, part = tid & 3;
  int2 rc = *(const int2*)(conn + 2 * k);           // x=rel, y=ent
  if (tid < 16) {
    short8 s = *(const short8*)(embb + (long)self_id * ED + tid * 8);
    #pragma unroll
    for (int j = 0; j < 8; ++j) sE[tid * 8 + j] = bf2f((u16)s[j]);
  }
  __syncthreads();

  const u16* er = embb + (long)rc.y * ED + part * 8;
  float dot = 0.f, sq = 0.f;
  #pragma unroll
  for (int i = 0; i < 4; ++i) {
    short8 e8 = *(const short8*)(er + i * 32);
    #pragma unroll
    for (int j = 0; j < 8; ++j) {
      float e = bf2f((u16)e8[j]);
      float s = sE[i * 32 + part * 8 + j];
      dot += e * s; sq += e * e;
    }
  }
  dot += __shfl_xor(dot, 1); dot += __shfl_xor(dot, 2);
  sq  += __shfl_xor(sq, 1);  sq  += __shfl_xor(sq, 2);
  if (part == 0) {
    float ne = fmaxf(sqrtf(sq), 1e-12f);
    float sim = dot / ne;
    if (rc.x == PADX) sim -= 1e9f;
    simS[k] = sim; relS[k] = rc.x; entS[k] = rc.y;
  }
  __syncthreads();

  if (tid < 64) {
    float my = simS[tid];
    int rank = 0;
    #pragma unroll
    for (int j = 0; j < 64; ++j) {
      float s = simS[j];                            // broadcast LDS read
      rank += ((s > my) || (s == my && j < tid)) ? 1 : 0;
    }
    bool val = (rank < KNB) && (relS[tid] != PADX);
    unsigned long long vm = __ballot(val ? 1 : 0);  // wave 0 only
    int cnt = __popcll(vm);
    long base = (long)b * 10;
    if (val) {
      int pos = __popcll(vm & ((1ull << tid) - 1ull));
      int2 p; p.x = relS[tid]; p.y = entS[tid];
      *(int2*)(idxA + (base + pos) * 2) = p;
    }
    if (tid >= cnt && tid < KNB) {
      int2 pp; pp.x = PADX; pp.y = PADX;            // PAD row of emb is all zeros
      *(int2*)(idxA + (base + tid) * 2) = pp;
    }
    if (tid == 0) meta[b] = cnt;
  }
  if (b == 0 && tid >= 64 && tid < 64 + 2 * (MROWS - MREAL)) {
    idxA[(long)MREAL * 2 + (tid - 64)] = PADX;      // pad rows -> zero emb row
  }
}

// ============ proj GEMM with fused gather: proj[M,128] = emb_bf16[idx] @ gcn_w^T ============
__global__ __launch_bounds__(256) void proj_gather_gemm(
    const int* __restrict__ idxA, const u16* __restrict__ embb,
    const u16* __restrict__ W, u16* __restrict__ proj)
{
  __shared__ u16 As[128 * 32];
  __shared__ u16 Bs[128 * 32];
  __shared__ int idxS[256];
  int tid = threadIdx.x;
  int bm = blockIdx.x;
  idxS[tid] = idxA[bm * 256 + tid];
  int lane = tid & 63, wave = tid >> 6;
  int wm = (wave & 1) * 64, wn = (wave >> 1) * 64;
  int col = lane & 15, quad = lane >> 4;

  floatx4 acc[4][4];
  #pragma unroll
  for (int i = 0; i < 4; ++i)
    #pragma unroll
    for (int j = 0; j < 4; ++j) { floatx4 z = {0.f,0.f,0.f,0.f}; acc[i][j] = z; }
  __syncthreads();

  for (int k0 = 0; k0 < 256; k0 += 32) {
    int half = k0 >> 7, koff = k0 & 127;
    #pragma unroll
    for (int t = 0; t < 2; ++t) {
      int c = t * 256 + tid;
      int rb = c >> 2, o = c & 3;
      int og = o ^ (rb & 3);
      gl2lds16(W + (long)rb * 256 + k0 + og * 8, &Bs[(size_t)c * 8]);
      int id = idxS[rb * 2 + half];
      gl2lds16(embb + (long)id * ED + koff + og * 8, &As[(size_t)c * 8]);
    }
    __syncthreads();
    short8 af[4], bfr[4];
    #pragma unroll
    for (int i = 0; i < 4; ++i) {
      int ra = wm + i * 16 + col;
      af[i] = *(const short8*)&As[(size_t)(ra * 4 + (quad ^ (ra & 3))) * 8];
      int rb = wn + i * 16 + col;
      bfr[i] = *(const short8*)&Bs[(size_t)(rb * 4 + (quad ^ (rb & 3))) * 8];
    }
    #pragma unroll
    for (int i = 0; i < 4; ++i)
      #pragma unroll
      for (int j = 0; j < 4; ++j)
        acc[i][j] = __builtin_amdgcn_mfma_f32_16x16x32_bf16(af[i], bfr[j], acc[i][j], 0, 0, 0);
    __syncthreads();
  }
  int gm0 = bm * 128 + wm + quad * 4;
  int gn0 = wn + col;
  #pragma unroll
  for (int i = 0; i < 4; ++i)
    #pragma unroll
    for (int j = 0; j < 4; ++j)
      #pragma unroll
      for (int rr = 0; rr < 4; ++rr)
        proj[(long)(gm0 + i * 16 + rr) * 128 + gn0 + j * 16] = f2bf(acc[i][j][rr]);
}

// ============ phase C: leaky/sum + gate MLP + tanh output ============
__global__ __launch_bounds__(128) void nbr_post_kernel(
    const int* __restrict__ query, const int* __restrict__ support,
    const int* __restrict__ q_deg_l, const int* __restrict__ q_deg_r,
    const int* __restrict__ s_deg_l, const int* __restrict__ s_deg_r,
    const float* __restrict__ emb,
    const u16* __restrict__ proj, const int* __restrict__ meta,
    const float* __restrict__ gcn_w_b, const float* __restrict__ gcn_b,
    const float* __restrict__ g1_w, const float* __restrict__ g1_b,
    const float* __restrict__ ln1_g, const float* __restrict__ ln1_b,
    const float* __restrict__ g2_w, const float* __restrict__ g2_b,
    const float* __restrict__ gate_temp,
    float* __restrict__ qv, u16* __restrict__ qv_bf)
{
  __shared__ __align__(16) float aggS[128];
  __shared__ float sEs[128];
  __shared__ float gateS;
  int tid = threadIdx.x, b = blockIdx.x;
  int deg, self_id, row, colb;
  if (b < BQ)              { int i = b;              deg = q_deg_l[i]; self_id = query[2*i];     row = i;        colb = 0;  }
  else if (b < 2*BQ)       { int i = b - BQ;         deg = q_deg_r[i]; self_id = query[2*i+1];   row = i;        colb = ED; }
  else if (b < 2*BQ+F_SUP) { int i = b - 2*BQ;       deg = s_deg_l[i]; self_id = support[2*i];   row = BQ + i;   colb = 0;  }
  else                     { int i = b - 2*BQ-F_SUP; deg = s_deg_r[i]; self_id = support[2*i+1]; row = BQ + i;   colb = ED; }
  float* outp = qv + (long)row * DM + colb;
  u16*  outpb = qv_bf + (long)row * DM + colb;

  int cnt = meta[b];
  float denom = fmaxf((float)cnt, 1.0f);
  float bsum = gcn_w_b[tid] + gcn_b[tid];
  float agg = 0.f;
  long pbase = (long)b * 10;
  for (int kk = 0; kk < cnt; ++kk) {
    float z = bf2f(proj[(pbase + kk) * 128 + tid]) + bsum;
    z = (z >= 0.f) ? z : 0.01f * z;
    agg += z;
  }
  agg /= denom;
  aggS[tid] = agg;
  sEs[tid] = emb[(long)self_id * ED + tid];
  __syncthreads();

  if (tid < 64) {
    int e = tid;
    const float4* g1r = (const float4*)(g1_w + e * ED);
    float y = g1_b[e];
    #pragma unroll 8
    for (int j = 0; j < 32; ++j) {
      float4 w = g1r[j];
      float4 a = *(const float4*)&aggS[j * 4];
      y += w.x*a.x + w.y*a.y + w.z*a.z + w.w*a.w;
    }
    float s = y;
    #pragma unroll
    for (int off = 1; off < 64; off <<= 1) s += __shfl_xor(s, off);
    float mean = s * (1.0f / 64.0f);
    float dv = y - mean;
    float s2 = dv * dv;
    #pragma unroll
    for (int off = 1; off < 64; off <<= 1) s2 += __shfl_xor(s2, off);
    float var = s2 * (1.0f / 64.0f);
    float hv = dv / sqrtf(var + 1e-5f) * ln1_g[e] + ln1_b[e];
    hv = fmaxf(hv, 0.f);
    float lp = hv * g2_w[e];
    #pragma unroll
    for (int off = 1; off < 64; off <<= 1) lp += __shfl_xor(lp, off);
    if (e == 0) {
      float logit = lp + g2_b[0];
      float temp = fminf(fmaxf(gate_temp[0], 0.1f), 5.0f);
      float gate = 1.0f / (1.0f + expf(-logit / temp));
      if (deg <= 0) gate = 0.f;
      gateS = gate;
    }
  }
  __syncthreads();
  float o = tanhf(sEs[tid] + gateS * aggS[tid]);
  outp[tid] = o;
  outpb[tid] = f2bf(o);
}

// ============ 64x64-tile MFMA GEMM (encoder): C = A @ W^T (+bias, relu) ============
__global__ __launch_bounds__(256) void gemm64(
    const u16* __restrict__ A, int lda,
    const u16* __restrict__ W, int ldw,
    int N, int K,
    float* __restrict__ Cout, u16* __restrict__ Cbf,
    const float* __restrict__ bias0, int relu)
{
  __shared__ u16 As[64 * 32];
  __shared__ u16 Bs[64 * 32];
  int tid = threadIdx.x;
  int nb = N >> 6;
  int bn = blockIdx.x % nb, bm = blockIdx.x / nb;
  int lane = tid & 63, wave = tid >> 6;
  int wm = (wave & 1) * 32, wn = (wave >> 1) * 32;
  int col = lane & 15, quad = lane >> 4;

  floatx4 acc[2][2];
  #pragma unroll
  for (int i = 0; i < 2; ++i)
    #pragma unroll
    for (int j = 0; j < 2; ++j) { floatx4 z = {0.f,0.f,0.f,0.f}; acc[i][j] = z; }

  for (int k0 = 0; k0 < K; k0 += 32) {
    {
      int r = tid >> 2, o = tid & 3;
      int og = o ^ (r & 3);
      gl2lds16(A + (long)(bm * 64 + r) * lda + k0 + og * 8, &As[(size_t)tid * 8]);
      gl2lds16(W + (long)(bn * 64 + r) * ldw + k0 + og * 8, &Bs[(size_t)tid * 8]);
    }
    __syncthreads();
    short8 af[2], bfr[2];
    #pragma unroll
    for (int i = 0; i < 2; ++i) {
      int ra = wm + i * 16 + col;
      af[i] = *(const short8*)&As[(size_t)(ra * 4 + (quad ^ (ra & 3))) * 8];
      int rb = wn + i * 16 + col;
      bfr[i] = *(const short8*)&Bs[(size_t)(rb * 4 + (quad ^ (rb & 3))) * 8];
    }
    #pragma unroll
    for (int i = 0; i < 2; ++i)
      #pragma unroll
      for (int j = 0; j < 2; ++j)
        acc[i][j] = __builtin_amdgcn_mfma_f32_16x16x32_bf16(af[i], bfr[j], acc[i][j], 0, 0, 0);
    __syncthreads();
  }

  int gm0 = bm * 64 + wm + quad * 4;
  int gn0 = bn * 64 + wn + col;
  #pragma unroll
  for (int i = 0; i < 2; ++i) {
    #pragma unroll
    for (int j = 0; j < 2; ++j) {
      int n = gn0 + j * 16;
      float bv = bias0 ? bias0[n] : 0.f;
      #pragma unroll
      for (int rr = 0; rr < 4; ++rr) {
        int m = gm0 + i * 16 + rr;
        float v = acc[i][j][rr] + bv;
        if (relu) v = fmaxf(v, 0.f);
        if (Cout) Cout[(long)m * N + n] = v;
        if (Cbf)  Cbf[(long)m * N + n] = f2bf(v);
      }
    }
  }
}

// ============ residual layernorm -> qe (fp32 + bf16), rows 0..4100 ============
__global__ __launch_bounds__(256) void ln_residual_kernel(
    const float* __restrict__ h2buf, const float* __restrict__ xbuf,
    const float* __restrict__ lng, const float* __restrict__ lnb,
    float* __restrict__ out, u16* __restrict__ outb)
{
  __shared__ float red[4];
  int r = blockIdx.x, tid = threadIdx.x;
  float v = h2buf[(long)r * DM + tid] + xbuf[(long)r * DM + tid];
  float s = v;
  #pragma unroll
  for (int off = 1; off < 64; off <<= 1) s += __shfl_xor(s, off);
  if ((tid & 63) == 0) red[tid >> 6] = s;
  __syncthreads();
  float mean = (red[0] + red[1] + red[2] + red[3]) * (1.0f / 256.0f);
  __syncthreads();
  float dv = v - mean;
  float s2 = dv * dv;
  #pragma unroll
  for (int off = 1; off < 64; off <<= 1) s2 += __shfl_xor(s2, off);
  if ((tid & 63) == 0) red[tid >> 6] = s2;
  __syncthreads();
  float var = (red[0] + red[1] + red[2] + red[3]) * (1.0f / 256.0f);
  float o = dv / sqrtf(var + 1e-5f) * lng[tid] + lnb[tid];
  out[(long)r * DM + tid] = o;
  outb[(long)r * DM + tid] = f2bf(o);
}

// ============ unified 64-row LSTM step kernel. mode: 2 first (+scorr rider), 1 mid,
// 3 last (+fused final dot; grid covers u<256 only). All modes share one geometry:
// block (bm: 64 rows, bn: 128 gate-cols), wave w1=row-half w2=col-half, so gq/cstate
// fragment order is NATIVE: fb=((bm*16+bn)*4+wave)*64+lane, 32 gq u16 + 8 c f32/thread.
// Permuted gate layout: p=bn*128+w2*64+j*16+col -> gate j, unit u=bn*32+w2*16+col.
__global__ __launch_bounds__(256) void lstm_step64(
    const u16* __restrict__ A,          // qe_bf (mode 2) or hbf (modes 1,3), ld=256
    const u16* __restrict__ W,          // wihb (mode 2) or whhb, ld=256
    const float* __restrict__ bias0,    // bihh (mode 2) or s_corr (permuted)
    u16* __restrict__ gq_fr, float* __restrict__ cstate,
    const float* __restrict__ qe,
    u16* __restrict__ hout,             // modes 1,2
    int mode,
    const float* __restrict__ sgv, float* __restrict__ dotv,   // mode 3
    const float* __restrict__ whh_f, float* __restrict__ sgo, float* __restrict__ sco) // mode 2 rider
{
  __shared__ u16 As[64 * 32];
  __shared__ u16 Bs[128 * 32];
  int tid = threadIdx.x;

  // ---- scorr rider blocks (mode 2 launch appends 512 blocks) ----
  if (mode == 2 && blockIdx.x >= gridDim.x - 512) {
    int sc = blockIdx.x - (gridDim.x - 512);
    float* sgS = (float*)As;                        // reuse LDS (256 floats fit in 4KB)
    float v = 0.f;
    #pragma unroll
    for (int r = 0; r < F_SUP; ++r) v += qe[(long)(BQ + r) * DM + tid];
    v *= (1.0f / (float)F_SUP);
    sgS[tid] = v;
    if (sc == 0) sgo[tid] = v;
    __syncthreads();
    int wv = tid >> 6, lane = tid & 63;
    int n = sc * 4 + wv;                            // orig row 0..2047
    float4 w = *(const float4*)(whh_f + (long)n * LH + DM + lane * 4);
    float4 s = *(const float4*)&sgS[lane * 4];
    float d = w.x*s.x + w.y*s.y + w.z*s.z + w.w*s.w;
    #pragma unroll
    for (int off = 1; off < 64; off <<= 1) d += __shfl_xor(d, off);
    if (lane == 0) {
      int g = n >> 9, uu = n & 511;
      int p = (uu >> 5) * 128 + ((uu >> 4) & 1) * 64 + g * 16 + (uu & 15);
      sco[p] = d;
    }
    return;
  }

  int bn, bm;
  if (mode == 3) { bn = blockIdx.x & 7;  bm = blockIdx.x >> 3; }   // 512 blocks, u<256
  else           { bn = blockIdx.x & 15; bm = blockIdx.x >> 4; }   // 1024 blocks
  int lane = tid & 63, wave = tid >> 6;
  int col = lane & 15, quad = (lane >> 4) & 3;
  int w1 = wave & 1, w2 = wave >> 1;
  int u = bn * 32 + w2 * 16 + col;
  long fb = ((long)(bm * 16 + bn) * 4 + wave) * 64 + lane;

  float scv[4];
  #pragma unroll
  for (int j = 0; j < 4; ++j)
    scv[j] = bias0[bn * 128 + w2 * 64 + j * 16 + col];

  u16 gqa[32]; float cpv[8];
  if (mode != 2) {
    const short8* gp = (const short8*)(gq_fr + fb * 32);
    #pragma unroll
    for (int t = 0; t < 4; ++t) *(short8*)&gqa[t * 8] = gp[t];
    const float4* cp = (const float4*)(cstate + fb * 8);
    #pragma unroll
    for (int t = 0; t < 2; ++t) *(float4*)&cpv[t * 4] = cp[t];
  }
  float qev[8];
  if (u < DM) {
    #pragma unroll
    for (int i = 0; i < 2; ++i)
      #pragma unroll
      for (int r = 0; r < 4; ++r) {
        int m = bm * 64 + w1 * 32 + i * 16 + quad * 4 + r;
        qev[i * 4 + r] = qe[(long)m * DM + u];
      }
  }
  float sgu = (mode == 3) ? sgv[u] : 0.f;

  floatx4 acc[2][4];
  #pragma unroll
  for (int i = 0; i < 2; ++i)
    #pragma unroll
    for (int j = 0; j < 4; ++j) { floatx4 z = {0.f,0.f,0.f,0.f}; acc[i][j] = z; }

  for (int k0 = 0; k0 < 256; k0 += 32) {
    {
      int r = tid >> 2, o = tid & 3;
      int og = o ^ (r & 3);
      gl2lds16(A + (long)(bm * 64 + r) * 256 + k0 + og * 8, &As[(size_t)tid * 8]);
    }
    #pragma unroll
    for (int t = 0; t < 2; ++t) {
      int c = t * 256 + tid;
      int r = c >> 2, o = c & 3;
      int og = o ^ (r & 3);
      gl2lds16(W + (long)(bn * 128 + r) * 256 + k0 + og * 8, &Bs[(size_t)c * 8]);
    }
    __syncthreads();
    short8 af[2], bfr[4];
    #pragma unroll
    for (int i = 0; i < 2; ++i) {
      int ra = w1 * 32 + i * 16 + col;
      af[i] = *(const short8*)&As[(size_t)(ra * 4 + (quad ^ (ra & 3))) * 8];
    }
    #pragma unroll
    for (int j = 0; j < 4; ++j) {
      int rb = w2 * 64 + j * 16 + col;
      bfr[j] = *(const short8*)&Bs[(size_t)(rb * 4 + (quad ^ (rb & 3))) * 8];
    }
    #pragma unroll
    for (int i = 0; i < 2; ++i)
      #pragma unroll
      for (int j = 0; j < 4; ++j)
        acc[i][j] = __builtin_amdgcn_mfma_f32_16x16x32_bf16(af[i], bfr[j], acc[i][j], 0, 0, 0);
    __syncthreads();
  }

  if (mode == 2) {
    // gq = acc+bias (bf16) -> regs+global; c = sig(I)*tanh(G) (c_prev=0); h write
    u16 ga[32];
    #pragma unroll
    for (int i = 0; i < 2; ++i)
      #pragma unroll
      for (int j = 0; j < 4; ++j)
        #pragma unroll
        for (int r = 0; r < 4; ++r)
          ga[(i * 4 + j) * 4 + r] = f2bf(acc[i][j][r] + scv[j]);
    short8* gp = (short8*)(gq_fr + fb * 32);
    #pragma unroll
    for (int t = 0; t < 4; ++t) gp[t] = *(short8*)&ga[t * 8];
    float cnew[8];
    #pragma unroll
    for (int i = 0; i < 2; ++i)
      #pragma unroll
      for (int r = 0; r < 4; ++r) {
        float gI = acc[i][0][r] + scv[0];
        float gG = acc[i][2][r] + scv[2];
        float gO = acc[i][3][r] + scv[3];
        float cn = sigf(gI) * tanh_fast(gG);
        cnew[i * 4 + r] = cn;
        if (u < DM) {
          int m = bm * 64 + w1 * 32 + i * 16 + quad * 4 + r;
          hout[(long)m * DM + u] = f2bf(qev[i * 4 + r] + sigf(gO) * tanh_fast(cn));
        }
      }
    float4* cp = (float4*)(cstate + fb * 8);
    #pragma unroll
    for (int t = 0; t < 2; ++t) cp[t] = *(float4*)&cnew[t * 4];
  } else if (mode == 1) {
    float cnew[8];
    #pragma unroll
    for (int i = 0; i < 2; ++i)
      #pragma unroll
      for (int r = 0; r < 4; ++r) {
        float gI = acc[i][0][r] + scv[0] + bf2f(gqa[(i * 4 + 0) * 4 + r]);
        float gF = acc[i][1][r] + scv[1] + bf2f(gqa[(i * 4 + 1) * 4 + r]);
        float gG = acc[i][2][r] + scv[2] + bf2f(gqa[(i * 4 + 2) * 4 + r]);
        float gO = acc[i][3][r] + scv[3] + bf2f(gqa[(i * 4 + 3) * 4 + r]);
        float cn = sigf(gF) * cpv[i * 4 + r] + sigf(gI) * tanh_fast(gG);
        cnew[i * 4 + r] = cn;
        if (u < DM) {
          int m = bm * 64 + w1 * 32 + i * 16 + quad * 4 + r;
          hout[(long)m * DM + u] = f2bf(qev[i * 4 + r] + sigf(gO) * tanh_fast(cn));
        }
      }
    float4* cp = (float4*)(cstate + fb * 8);
    #pragma unroll
    for (int t = 0; t < 2; ++t) cp[t] = *(float4*)&cnew[t * 4];
  } else {
    // mode 3: c,h dead after; dot with sg, 16-lane reduce, one atomic per row-frag
    #pragma unroll
    for (int i = 0; i < 2; ++i) {
      #pragma unroll
      for (int r = 0; r < 4; ++r) {
        float gI = acc[i][0][r] + scv[0] + bf2f(gqa[(i * 4 + 0) * 4 + r]);
        float gF = acc[i][1][r] + scv[1] + bf2f(gqa[(i * 4 + 1) * 4 + r]);
        float gG = acc[i][2][r] + scv[2] + bf2f(gqa[(i * 4 + 2) * 4 + r]);
        float gO = acc[i][3][r] + scv[3] + bf2f(gqa[(i * 4 + 3) * 4 + r]);
        float cn = sigf(gF) * cpv[i * 4 + r] + sigf(gI) * tanh_fast(gG);
        float hv = qev[i * 4 + r] + sigf(gO) * tanh_fast(cn);
        float p = hv * sgu;
        p += __shfl_xor(p, 1); p += __shfl_xor(p, 2);
        p += __shfl_xor(p, 4); p += __shfl_xor(p, 8);
        if (col == 0) {
          int m = bm * 64 + w1 * 32 + i * 16 + quad * 4 + r;
          atomicAdd(&dotv[m], p);
        }
      }
    }
  }
}

extern "C" void kernel_launch(void* const* d_in, const int* in_sizes, int n_in,
                              void* d_out, int out_size, void* d_ws, size_t ws_size,
                              hipStream_t stream)
{
  const int*   query    = (const int*)  d_in[0];
  const int*   support  = (const int*)  d_in[1];
  const int*   q_l1     = (const int*)  d_in[2];
  const int*   q_deg_l  = (const int*)  d_in[3];
  const int*   q_r1     = (const int*)  d_in[4];
  const int*   q_deg_r  = (const int*)  d_in[5];
  const int*   s_l1     = (const int*)  d_in[6];
  const int*   s_deg_l  = (const int*)  d_in[7];
  const int*   s_r1     = (const int*)  d_in[8];
  const int*   s_deg_r  = (const int*)  d_in[9];
  const float* symbol_emb = (const float*)d_in[10];
  const float* gcn_w_w  = (const float*)d_in[11];
  const float* gcn_w_b  = (const float*)d_in[12];
  const float* gcn_b    = (const float*)d_in[13];
  const float* g1_w     = (const float*)d_in[14];
  const float* g1_b     = (const float*)d_in[15];
  const float* ln1_g    = (const float*)d_in[16];
  const float* ln1_b    = (const float*)d_in[17];
  const float* g2_w     = (const float*)d_in[18];
  const float* g2_b     = (const float*)d_in[19];
  const float* gate_temp= (const float*)d_in[20];
  const float* se_p1_w  = (const float*)d_in[21];
  const float* se_p1_b  = (const float*)d_in[22];
  const float* se_p2_w  = (const float*)d_in[23];
  const float* se_p2_b  = (const float*)d_in[24];
  const float* se_ln_g  = (const float*)d_in[25];
  const float* se_ln_b  = (const float*)d_in[26];
  const float* w_ih     = (const float*)d_in[27];
  const float* w_hh     = (const float*)d_in[28];
  const float* b_ih     = (const float*)d_in[29];
  const float* b_hh     = (const float*)d_in[30];

  float* ws = (float*)d_ws;
  size_t off = 0;
  float* projF   = ws + off; off += (size_t)MROWS * 128 / 2;      // bf16 proj
  float* idxF    = ws + off; off += (size_t)MROWS * 2;
  float* qv      = ws + off; off += (size_t)MQ * DM;
  float* qe      = ws + off; off += (size_t)MQ * DM;
  float* qv_bfF  = ws + off; off += (size_t)MQ * DM / 2;
  float* qe_bfF  = ws + off; off += (size_t)MQ * DM / 2;
  float* h1bF    = ws + off; off += (size_t)MQ * DI / 2;
  float* H2      = ws + off; off += (size_t)MQ * DM;
  float* gqbF    = ws + off; off += (size_t)BQ * NG / 2;          // fragment-order gates (bf16)
  float* cstate  = ws + off; off += (size_t)BQ * LH;              // fragment-order c (fp32)
  float* hbf0F   = ws + off; off += (size_t)BQ * DM / 2;
  float* hbf1F   = ws + off; off += (size_t)BQ * DM / 2;
  float* p1bF    = ws + off; off += 131072 / 2;
  float* p2bF    = ws + off; off += 131072 / 2;
  float* gcnbF   = ws + off; off += 32768 / 2;
  float* wihbF   = ws + off; off += 524288 / 2;
  float* whhbF   = ws + off; off += 524288 / 2;
  float* bihh    = ws + off; off += 2048;
  float* sg      = ws + off; off += 256;
  float* s_corr  = ws + off; off += 2048;
  float* metaF   = ws + off; off += 8448;
  float* embbF   = ws + off; off += (size_t)EMB_ELEMS / 2;        // bf16 symbol table (51 MB)

  u16* proj   = (u16*)projF;
  int* idxA   = (int*)idxF;
  u16* qv_bf  = (u16*)qv_bfF;
  u16* qe_bf  = (u16*)qe_bfF;
  u16* H1_bf  = (u16*)h1bF;
  u16* gq_fr  = (u16*)gqbF;
  u16* hbf0   = (u16*)hbf0F;
  u16* hbf1   = (u16*)hbf1F;
  u16* p1b    = (u16*)p1bF;
  u16* p2b    = (u16*)p2bF;
  u16* gcnb   = (u16*)gcnbF;
  u16* wihb   = (u16*)wihbF;
  u16* whhb   = (u16*)whhbF;
  int* meta   = (int*)metaF;
  u16* embb   = (u16*)embbF;

  // 0. all casts/permutes + bf16 symbol table + d_out zero (one launch)
  {
    long total = (long)NEMB8 + 1345536 + BQ;
    int blocks = (int)((total + 255) / 256);
    prep_all<<<blocks, 256, 0, stream>>>(symbol_emb, embb,
        se_p1_w, se_p2_w, gcn_w_w, w_ih, w_hh, b_ih, b_hh,
        p1b, p2b, gcnb, wihb, whhb, bihh, (float*)d_out);
  }

  // 1. bf16 gather + sims + fused rank/select -> idxA/meta
  nbr_simrank_kernel<<<NBTOT, 256, 0, stream>>>(
      query, support, q_l1, q_r1, s_l1, s_r1, embb, idxA, meta);

  // 2. proj = emb_bf16[idx] @ gcn_w^T   (M=82048, N=128, K=256), gather via global_load_lds
  proj_gather_gemm<<<MROWS / 128, 256, 0, stream>>>(idxA, embb, gcnb, proj);

  // 3. leaky/sum + gate MLP + tanh -> qv rows 0..4100 (query + support)
  nbr_post_kernel<<<NBTOT, 128, 0, stream>>>(
      query, support, q_deg_l, q_deg_r, s_deg_l, s_deg_r, symbol_emb,
      proj, meta, gcn_w_b, gcn_b, g1_w, g1_b, ln1_g, ln1_b, g2_w, g2_b, gate_temp,
      qv, qv_bf);

  // 4. encoder (query + 5 support rows ride along) -- 64x64 tiles for occupancy
  gemm64<<<(MQ / 64) * (DI / 64), 256, 0, stream>>>(qv_bf, 256, p1b, 256, DI, 256,
      nullptr, H1_bf, se_p1_b, 1);
  gemm64<<<(MQ / 64) * (DM / 64), 256, 0, stream>>>(H1_bf, 512, p2b, 512, DM, 512,
      H2, nullptr, se_p2_b, 0);
  ln_residual_kernel<<<BQ + F_SUP, 256, 0, stream>>>(H2, qv, se_ln_g, se_ln_b, qe, qe_bf);

  // 5. LSTM step 1 (mode 2): 64x16=1024 tile blocks + 512 scorr-rider blocks (4/CU)
  lstm_step64<<<1024 + 512, 256, 0, stream>>>(qe_bf, wihb, bihh, gq_fr, cstate, qe,
      hbf0, 2, nullptr, nullptr, w_hh, sg, s_corr);

  // 6. steps 2..3 (mode 1): 1024 blocks each, h ping-pong
  lstm_step64<<<1024, 256, 0, stream>>>(hbf0, whhb, s_corr, gq_fr, cstate, qe,
      hbf1, 1, nullptr, nullptr, nullptr, nullptr, nullptr);
  lstm_step64<<<1024, 256, 0, stream>>>(hbf1, whhb, s_corr, gq_fr, cstate, qe,
      hbf0, 1, nullptr, nullptr, nullptr, nullptr, nullptr);

  // 7. step 4 + fused final dot (mode 3): 512 blocks, u<256 only, no c/h stores
  lstm_step64<<<512, 256, 0, stream>>>(hbf0, whhb, s_corr, gq_fr, cstate, qe,
      nullptr, 3, sg, (float*)d_out, nullptr, nullptr, nullptr);
}

// Round 9
// 380.759 us; speedup vs baseline: 2.3991x; 1.0072x over previous
//
#include <hip/hip_runtime.h>
#include <math.h>

#define BQ 4096
#define F_SUP 5
#define MAXK 64
#define ED 128
#define DM 256
#define DI 512
#define LH 512
#define NG 2048
#define PADX 200000
#define KNB 10
#define NBTOT 8202            // 2*BQ + 2*F_SUP neighbor groups
#define MROWS 82048           // 8202*10 padded to 641*128
#define MREAL 82020
#define MQ 4224               // 4101 rows padded to 33*128
#define EMB_ELEMS 25600128    // 200001*128
#define NEMB8 3200016         // EMB_ELEMS/8

typedef unsigned short u16;
typedef __attribute__((ext_vector_type(8))) short short8;
typedef __attribute__((ext_vector_type(4))) float floatx4;

__device__ __forceinline__ float sigf(float x) { return 1.0f / (1.0f + __expf(-x)); }
__device__ __forceinline__ float tanh_fast(float x) {
  float a = fabsf(x);
  float e = __expf(-2.0f * a);
  float t = (1.0f - e) / (1.0f + e);
  return copysignf(t, x);
}
__device__ __forceinline__ u16 f2bf(float f) {
  unsigned u = __float_as_uint(f);
  unsigned r = (u + 0x7FFFu + ((u >> 16) & 1u)) >> 16;
  return (u16)r;
}
__device__ __forceinline__ float bf2f(u16 u) {
  return __uint_as_float(((unsigned)u) << 16);
}
__device__ __forceinline__ void gl2lds16(const void* g, void* l) {
  __builtin_amdgcn_global_load_lds(
      (const __attribute__((address_space(1))) void*)g,
      (__attribute__((address_space(3))) void*)l, 16, 0, 0);
}

// ============ phase 0: ALL weight casts/permutes + bf16 symbol table + d_out zero ============
__global__ __launch_bounds__(256) void prep_all(
    const float* __restrict__ emb, u16* __restrict__ embb,
    const float* __restrict__ p1, const float* __restrict__ p2,
    const float* __restrict__ gcnw, const float* __restrict__ wih,
    const float* __restrict__ whh, const float* __restrict__ bih,
    const float* __restrict__ bhh,
    u16* __restrict__ p1b, u16* __restrict__ p2b, u16* __restrict__ gcnb,
    u16* __restrict__ wihb, u16* __restrict__ whhb, float* __restrict__ bihh,
    float* __restrict__ outz)
{
  long gid = (long)blockIdx.x * 256 + threadIdx.x;
  if (gid < (long)NEMB8) {
    long i = gid * 8;
    float4 f0 = *(const float4*)(emb + i);
    float4 f1 = *(const float4*)(emb + i + 4);
    short8 s;
    s[0]=(short)f2bf(f0.x); s[1]=(short)f2bf(f0.y); s[2]=(short)f2bf(f0.z); s[3]=(short)f2bf(f0.w);
    s[4]=(short)f2bf(f1.x); s[5]=(short)f2bf(f1.y); s[6]=(short)f2bf(f1.z); s[7]=(short)f2bf(f1.w);
    *(short8*)(embb + i) = s;
    return;
  }
  int g2 = (int)(gid - NEMB8);
  if (g2 < 131072) { p1b[g2] = f2bf(p1[g2]); }
  else if (g2 < 262144) { int i = g2 - 131072; p2b[i] = f2bf(p2[i]); }
  else if (g2 < 294912) { int i = g2 - 262144; gcnb[i] = f2bf(gcnw[i]); }
  else if (g2 < 819200) {
    int i = g2 - 294912; int p = i >> 8, k = i & 255;
    int g = (p >> 4) & 3, uu = (p >> 7) * 32 + ((p >> 6) & 1) * 16 + (p & 15);
    int n = g * 512 + uu;
    wihb[i] = f2bf(wih[(long)n * DM + k]);
  } else if (g2 < 1343488) {
    int i = g2 - 819200; int p = i >> 8, k = i & 255;
    int g = (p >> 4) & 3, uu = (p >> 7) * 32 + ((p >> 6) & 1) * 16 + (p & 15);
    int n = g * 512 + uu;
    whhb[i] = f2bf(whh[(long)n * LH + k]);
  } else if (g2 < 1345536) {
    int p = g2 - 1343488;
    int g = (p >> 4) & 3, uu = (p >> 7) * 32 + ((p >> 6) & 1) * 16 + (p & 15);
    int n = g * 512 + uu;
    bihh[p] = bih[n] + bhh[n];
  } else if (g2 < 1345536 + BQ) {
    outz[g2 - 1345536] = 0.f;                       // final dot accumulates atomically
  }
}

// ============ phase A: bf16 gather + sims + fused rank/select ============
__global__ __launch_bounds__(256) void nbr_simrank_kernel(
    const int* __restrict__ query, const int* __restrict__ support,
    const int* __restrict__ q_l1, const int* __restrict__ q_r1,
    const int* __restrict__ s_l1, const int* __restrict__ s_r1,
    const u16* __restrict__ embb, int* __restrict__ idxA, int* __restrict__ meta)
{
  __shared__ float sE[128];
  __shared__ float simS[64];
  __shared__ int relS[64], entS[64];
  int tid = threadIdx.x;
  int b = blockIdx.x;
  const int* conn; int self_id;
  if (b < BQ)              { int i = b;              conn = q_l1 + (long)i*(MAXK*2); self_id = query[2*i];   }
  else if (b < 2*BQ)       { int i = b - BQ;         conn = q_r1 + (long)i*(MAXK*2); self_id = query[2*i+1]; }
  else if (b < 2*BQ+F_SUP) { int i = b - 2*BQ;       conn = s_l1 + (long)i*(MAXK*2); self_id = support[2*i]; }
  else                     { int i = b - 2*BQ-F_SUP; conn = s_r1 + (long)i*(MAXK*2); self_id = support[2*i+1]; }

  int k = tid >> 2, part = tid & 3;
  int2 rc = *(const int2*)(conn + 2 * k);           // x=rel, y=ent
  if (tid < 16) {
    short8 s = *(const short8*)(embb + (long)self_id * ED + tid * 8);
    #pragma unroll
    for (int j = 0; j < 8; ++j) sE[tid * 8 + j] = bf2f((u16)s[j]);
  }
  __syncthreads();

  const u16* er = embb + (long)rc.y * ED + part * 8;
  float dot = 0.f, sq = 0.f;
  #pragma unroll
  for (int i = 0; i < 4; ++i) {
    short8 e8 = *(const short8*)(er + i * 32);
    #pragma unroll
    for (int j = 0; j < 8; ++j) {
      float e = bf2f((u16)e8[j]);
      float s = sE[i * 32 + part * 8 + j];
      dot += e * s; sq += e * e;
    }
  }
  dot += __shfl_xor(dot, 1); dot += __shfl_xor(dot, 2);
  sq  += __shfl_xor(sq, 1);  sq  += __shfl_xor(sq, 2);
  if (part == 0) {
    float ne = fmaxf(sqrtf(sq), 1e-12f);
    float sim = dot / ne;
    if (rc.x == PADX) sim -= 1e9f;
    simS[k] = sim; relS[k] = rc.x; entS[k] = rc.y;
  }
  __syncthreads();

  if (tid < 64) {
    float my = simS[tid];
    int rank = 0;
    #pragma unroll
    for (int j = 0; j < 64; ++j) {
      float s = simS[j];                            // broadcast LDS read
      rank += ((s > my) || (s == my && j < tid)) ? 1 : 0;
    }
    bool val = (rank < KNB) && (relS[tid] != PADX);
    unsigned long long vm = __ballot(val ? 1 : 0);  // wave 0 only
    int cnt = __popcll(vm);
    long base = (long)b * 10;
    if (val) {
      int pos = __popcll(vm & ((1ull << tid) - 1ull));
      int2 p; p.x = relS[tid]; p.y = entS[tid];
      *(int2*)(idxA + (base + pos) * 2) = p;
    }
    if (tid >= cnt && tid < KNB) {
      int2 pp; pp.x = PADX; pp.y = PADX;            // PAD row of emb is all zeros
      *(int2*)(idxA + (base + tid) * 2) = pp;
    }
    if (tid == 0) meta[b] = cnt;
  }
  if (b == 0 && tid >= 64 && tid < 64 + 2 * (MROWS - MREAL)) {
    idxA[(long)MREAL * 2 + (tid - 64)] = PADX;      // pad rows -> zero emb row
  }
}

// ============ proj GEMM with fused gather: proj[M,128] = emb_bf16[idx] @ gcn_w^T ============
// 64-row tiles -> 1282 blocks (5/CU), 12 KB LDS. 4 waves: w1=row-half(32), w2=col-half(64),
// per wave acc 2x4 (32x64). Same staging/swizzle scheme as lstm_step64 (verified geometry).
__global__ __launch_bounds__(256) void proj_gather_gemm(
    const int* __restrict__ idxA, const u16* __restrict__ embb,
    const u16* __restrict__ W, u16* __restrict__ proj)
{
  __shared__ u16 As[64 * 32];
  __shared__ u16 Bs[128 * 32];
  __shared__ int idxS[128];
  int tid = threadIdx.x;
  int bm = blockIdx.x;
  if (tid < 128) idxS[tid] = idxA[bm * 128 + tid];
  int lane = tid & 63, wave = tid >> 6;
  int w1 = wave & 1, w2 = wave >> 1;
  int col = lane & 15, quad = lane >> 4;

  floatx4 acc[2][4];
  #pragma unroll
  for (int i = 0; i < 2; ++i)
    #pragma unroll
    for (int j = 0; j < 4; ++j) { floatx4 z = {0.f,0.f,0.f,0.f}; acc[i][j] = z; }
  __syncthreads();

  for (int k0 = 0; k0 < 256; k0 += 32) {
    int half = k0 >> 7, koff = k0 & 127;
    {
      int r = tid >> 2, o = tid & 3;
      int og = o ^ (r & 3);
      int id = idxS[r * 2 + half];
      gl2lds16(embb + (long)id * ED + koff + og * 8, &As[(size_t)tid * 8]);
    }
    #pragma unroll
    for (int t = 0; t < 2; ++t) {
      int c = t * 256 + tid;
      int rb = c >> 2, o = c & 3;
      int og = o ^ (rb & 3);
      gl2lds16(W + (long)rb * 256 + k0 + og * 8, &Bs[(size_t)c * 8]);
    }
    __syncthreads();
    short8 af[2], bfr[4];
    #pragma unroll
    for (int i = 0; i < 2; ++i) {
      int ra = w1 * 32 + i * 16 + col;
      af[i] = *(const short8*)&As[(size_t)(ra * 4 + (quad ^ (ra & 3))) * 8];
    }
    #pragma unroll
    for (int j = 0; j < 4; ++j) {
      int rb = w2 * 64 + j * 16 + col;
      bfr[j] = *(const short8*)&Bs[(size_t)(rb * 4 + (quad ^ (rb & 3))) * 8];
    }
    #pragma unroll
    for (int i = 0; i < 2; ++i)
      #pragma unroll
      for (int j = 0; j < 4; ++j)
        acc[i][j] = __builtin_amdgcn_mfma_f32_16x16x32_bf16(af[i], bfr[j], acc[i][j], 0, 0, 0);
    __syncthreads();
  }
  int gm0 = bm * 64 + w1 * 32 + quad * 4;
  int gn0 = w2 * 64 + col;
  #pragma unroll
  for (int i = 0; i < 2; ++i)
    #pragma unroll
    for (int j = 0; j < 4; ++j)
      #pragma unroll
      for (int rr = 0; rr < 4; ++rr)
        proj[(long)(gm0 + i * 16 + rr) * 128 + gn0 + j * 16] = f2bf(acc[i][j][rr]);
}

// ============ phase C: leaky/sum + gate MLP + tanh output ============
__global__ __launch_bounds__(128) void nbr_post_kernel(
    const int* __restrict__ query, const int* __restrict__ support,
    const int* __restrict__ q_deg_l, const int* __restrict__ q_deg_r,
    const int* __restrict__ s_deg_l, const int* __restrict__ s_deg_r,
    const float* __restrict__ emb,
    const u16* __restrict__ proj, const int* __restrict__ meta,
    const float* __restrict__ gcn_w_b, const float* __restrict__ gcn_b,
    const float* __restrict__ g1_w, const float* __restrict__ g1_b,
    const float* __restrict__ ln1_g, const float* __restrict__ ln1_b,
    const float* __restrict__ g2_w, const float* __restrict__ g2_b,
    const float* __restrict__ gate_temp,
    float* __restrict__ qv, u16* __restrict__ qv_bf)
{
  __shared__ __align__(16) float aggS[128];
  __shared__ float sEs[128];
  __shared__ float gateS;
  int tid = threadIdx.x, b = blockIdx.x;
  int deg, self_id, row, colb;
  if (b < BQ)              { int i = b;              deg = q_deg_l[i]; self_id = query[2*i];     row = i;        colb = 0;  }
  else if (b < 2*BQ)       { int i = b - BQ;         deg = q_deg_r[i]; self_id = query[2*i+1];   row = i;        colb = ED; }
  else if (b < 2*BQ+F_SUP) { int i = b - 2*BQ;       deg = s_deg_l[i]; self_id = support[2*i];   row = BQ + i;   colb = 0;  }
  else                     { int i = b - 2*BQ-F_SUP; deg = s_deg_r[i]; self_id = support[2*i+1]; row = BQ + i;   colb = ED; }
  float* outp = qv + (long)row * DM + colb;
  u16*  outpb = qv_bf + (long)row * DM + colb;

  int cnt = meta[b];
  float denom = fmaxf((float)cnt, 1.0f);
  float bsum = gcn_w_b[tid] + gcn_b[tid];
  float agg = 0.f;
  long pbase = (long)b * 10;
  for (int kk = 0; kk < cnt; ++kk) {
    float z = bf2f(proj[(pbase + kk) * 128 + tid]) + bsum;
    z = (z >= 0.f) ? z : 0.01f * z;
    agg += z;
  }
  agg /= denom;
  aggS[tid] = agg;
  sEs[tid] = emb[(long)self_id * ED + tid];
  __syncthreads();

  if (tid < 64) {
    int e = tid;
    const float4* g1r = (const float4*)(g1_w + e * ED);
    float y = g1_b[e];
    #pragma unroll 8
    for (int j = 0; j < 32; ++j) {
      float4 w = g1r[j];
      float4 a = *(const float4*)&aggS[j * 4];
      y += w.x*a.x + w.y*a.y + w.z*a.z + w.w*a.w;
    }
    float s = y;
    #pragma unroll
    for (int off = 1; off < 64; off <<= 1) s += __shfl_xor(s, off);
    float mean = s * (1.0f / 64.0f);
    float dv = y - mean;
    float s2 = dv * dv;
    #pragma unroll
    for (int off = 1; off < 64; off <<= 1) s2 += __shfl_xor(s2, off);
    float var = s2 * (1.0f / 64.0f);
    float hv = dv / sqrtf(var + 1e-5f) * ln1_g[e] + ln1_b[e];
    hv = fmaxf(hv, 0.f);
    float lp = hv * g2_w[e];
    #pragma unroll
    for (int off = 1; off < 64; off <<= 1) lp += __shfl_xor(lp, off);
    if (e == 0) {
      float logit = lp + g2_b[0];
      float temp = fminf(fmaxf(gate_temp[0], 0.1f), 5.0f);
      float gate = 1.0f / (1.0f + expf(-logit / temp));
      if (deg <= 0) gate = 0.f;
      gateS = gate;
    }
  }
  __syncthreads();
  float o = tanhf(sEs[tid] + gateS * aggS[tid]);
  outp[tid] = o;
  outpb[tid] = f2bf(o);
}

// ============ 64x64-tile MFMA GEMM (encoder): C = A @ W^T (+bias, relu) ============
__global__ __launch_bounds__(256) void gemm64(
    const u16* __restrict__ A, int lda,
    const u16* __restrict__ W, int ldw,
    int N, int K,
    float* __restrict__ Cout, u16* __restrict__ Cbf,
    const float* __restrict__ bias0, int relu)
{
  __shared__ u16 As[64 * 32];
  __shared__ u16 Bs[64 * 32];
  int tid = threadIdx.x;
  int nb = N >> 6;
  int bn = blockIdx.x % nb, bm = blockIdx.x / nb;
  int lane = tid & 63, wave = tid >> 6;
  int wm = (wave & 1) * 32, wn = (wave >> 1) * 32;
  int col = lane & 15, quad = lane >> 4;

  floatx4 acc[2][2];
  #pragma unroll
  for (int i = 0; i < 2; ++i)
    #pragma unroll
    for (int j = 0; j < 2; ++j) { floatx4 z = {0.f,0.f,0.f,0.f}; acc[i][j] = z; }

  for (int k0 = 0; k0 < K; k0 += 32) {
    {
      int r = tid >> 2, o = tid & 3;
      int og = o ^ (r & 3);
      gl2lds16(A + (long)(bm * 64 + r) * lda + k0 + og * 8, &As[(size_t)tid * 8]);
      gl2lds16(W + (long)(bn * 64 + r) * ldw + k0 + og * 8, &Bs[(size_t)tid * 8]);
    }
    __syncthreads();
    short8 af[2], bfr[2];
    #pragma unroll
    for (int i = 0; i < 2; ++i) {
      int ra = wm + i * 16 + col;
      af[i] = *(const short8*)&As[(size_t)(ra * 4 + (quad ^ (ra & 3))) * 8];
      int rb = wn + i * 16 + col;
      bfr[i] = *(const short8*)&Bs[(size_t)(rb * 4 + (quad ^ (rb & 3))) * 8];
    }
    #pragma unroll
    for (int i = 0; i < 2; ++i)
      #pragma unroll
      for (int j = 0; j < 2; ++j)
        acc[i][j] = __builtin_amdgcn_mfma_f32_16x16x32_bf16(af[i], bfr[j], acc[i][j], 0, 0, 0);
    __syncthreads();
  }

  int gm0 = bm * 64 + wm + quad * 4;
  int gn0 = bn * 64 + wn + col;
  #pragma unroll
  for (int i = 0; i < 2; ++i) {
    #pragma unroll
    for (int j = 0; j < 2; ++j) {
      int n = gn0 + j * 16;
      float bv = bias0 ? bias0[n] : 0.f;
      #pragma unroll
      for (int rr = 0; rr < 4; ++rr) {
        int m = gm0 + i * 16 + rr;
        float v = acc[i][j][rr] + bv;
        if (relu) v = fmaxf(v, 0.f);
        if (Cout) Cout[(long)m * N + n] = v;
        if (Cbf)  Cbf[(long)m * N + n] = f2bf(v);
      }
    }
  }
}

// ============ residual layernorm -> qe (fp32 + bf16), rows 0..4100 ============
__global__ __launch_bounds__(256) void ln_residual_kernel(
    const float* __restrict__ h2buf, const float* __restrict__ xbuf,
    const float* __restrict__ lng, const float* __restrict__ lnb,
    float* __restrict__ out, u16* __restrict__ outb)
{
  __shared__ float red[4];
  int r = blockIdx.x, tid = threadIdx.x;
  float v = h2buf[(long)r * DM + tid] + xbuf[(long)r * DM + tid];
  float s = v;
  #pragma unroll
  for (int off = 1; off < 64; off <<= 1) s += __shfl_xor(s, off);
  if ((tid & 63) == 0) red[tid >> 6] = s;
  __syncthreads();
  float mean = (red[0] + red[1] + red[2] + red[3]) * (1.0f / 256.0f);
  __syncthreads();
  float dv = v - mean;
  float s2 = dv * dv;
  #pragma unroll
  for (int off = 1; off < 64; off <<= 1) s2 += __shfl_xor(s2, off);
  if ((tid & 63) == 0) red[tid >> 6] = s2;
  __syncthreads();
  float var = (red[0] + red[1] + red[2] + red[3]) * (1.0f / 256.0f);
  float o = dv / sqrtf(var + 1e-5f) * lng[tid] + lnb[tid];
  out[(long)r * DM + tid] = o;
  outb[(long)r * DM + tid] = f2bf(o);
}

// ============ unified 64-row LSTM step kernel. mode: 2 first (+scorr rider), 1 mid,
// 3 last (+fused final dot; grid covers u<256 only). All modes share one geometry:
// block (bm: 64 rows, bn: 128 gate-cols), wave w1=row-half w2=col-half, so gq/cstate
// fragment order is NATIVE: fb=((bm*16+bn)*4+wave)*64+lane, 32 gq u16 + 8 c f32/thread.
// Permuted gate layout: p=bn*128+w2*64+j*16+col -> gate j, unit u=bn*32+w2*16+col.
__global__ __launch_bounds__(256) void lstm_step64(
    const u16* __restrict__ A,          // qe_bf (mode 2) or hbf (modes 1,3), ld=256
    const u16* __restrict__ W,          // wihb (mode 2) or whhb, ld=256
    const float* __restrict__ bias0,    // bihh (mode 2) or s_corr (permuted)
    u16* __restrict__ gq_fr, float* __restrict__ cstate,
    const float* __restrict__ qe,
    u16* __restrict__ hout,             // modes 1,2
    int mode,
    const float* __restrict__ sgv, float* __restrict__ dotv,   // mode 3
    const float* __restrict__ whh_f, float* __restrict__ sgo, float* __restrict__ sco) // mode 2 rider
{
  __shared__ u16 As[64 * 32];
  __shared__ u16 Bs[128 * 32];
  int tid = threadIdx.x;

  // ---- scorr rider blocks (mode 2 launch appends 512 blocks) ----
  if (mode == 2 && blockIdx.x >= gridDim.x - 512) {
    int sc = blockIdx.x - (gridDim.x - 512);
    float* sgS = (float*)As;                        // reuse LDS (256 floats fit in 4KB)
    float v = 0.f;
    #pragma unroll
    for (int r = 0; r < F_SUP; ++r) v += qe[(long)(BQ + r) * DM + tid];
    v *= (1.0f / (float)F_SUP);
    sgS[tid] = v;
    if (sc == 0) sgo[tid] = v;
    __syncthreads();
    int wv = tid >> 6, lane = tid & 63;
    int n = sc * 4 + wv;                            // orig row 0..2047
    float4 w = *(const float4*)(whh_f + (long)n * LH + DM + lane * 4);
    float4 s = *(const float4*)&sgS[lane * 4];
    float d = w.x*s.x + w.y*s.y + w.z*s.z + w.w*s.w;
    #pragma unroll
    for (int off = 1; off < 64; off <<= 1) d += __shfl_xor(d, off);
    if (lane == 0) {
      int g = n >> 9, uu = n & 511;
      int p = (uu >> 5) * 128 + ((uu >> 4) & 1) * 64 + g * 16 + (uu & 15);
      sco[p] = d;
    }
    return;
  }

  int bn, bm;
  if (mode == 3) { bn = blockIdx.x & 7;  bm = blockIdx.x >> 3; }   // 512 blocks, u<256
  else           { bn = blockIdx.x & 15; bm = blockIdx.x >> 4; }   // 1024 blocks
  int lane = tid & 63, wave = tid >> 6;
  int col = lane & 15, quad = (lane >> 4) & 3;
  int w1 = wave & 1, w2 = wave >> 1;
  int u = bn * 32 + w2 * 16 + col;
  long fb = ((long)(bm * 16 + bn) * 4 + wave) * 64 + lane;

  float scv[4];
  #pragma unroll
  for (int j = 0; j < 4; ++j)
    scv[j] = bias0[bn * 128 + w2 * 64 + j * 16 + col];

  u16 gqa[32]; float cpv[8];
  if (mode != 2) {
    const short8* gp = (const short8*)(gq_fr + fb * 32);
    #pragma unroll
    for (int t = 0; t < 4; ++t) *(short8*)&gqa[t * 8] = gp[t];
    const float4* cp = (const float4*)(cstate + fb * 8);
    #pragma unroll
    for (int t = 0; t < 2; ++t) *(float4*)&cpv[t * 4] = cp[t];
  }
  float qev[8];
  if (u < DM) {
    #pragma unroll
    for (int i = 0; i < 2; ++i)
      #pragma unroll
      for (int r = 0; r < 4; ++r) {
        int m = bm * 64 + w1 * 32 + i * 16 + quad * 4 + r;
        qev[i * 4 + r] = qe[(long)m * DM + u];
      }
  }
  float sgu = (mode == 3) ? sgv[u] : 0.f;

  floatx4 acc[2][4];
  #pragma unroll
  for (int i = 0; i < 2; ++i)
    #pragma unroll
    for (int j = 0; j < 4; ++j) { floatx4 z = {0.f,0.f,0.f,0.f}; acc[i][j] = z; }

  for (int k0 = 0; k0 < 256; k0 += 32) {
    {
      int r = tid >> 2, o = tid & 3;
      int og = o ^ (r & 3);
      gl2lds16(A + (long)(bm * 64 + r) * 256 + k0 + og * 8, &As[(size_t)tid * 8]);
    }
    #pragma unroll
    for (int t = 0; t < 2; ++t) {
      int c = t * 256 + tid;
      int r = c >> 2, o = c & 3;
      int og = o ^ (r & 3);
      gl2lds16(W + (long)(bn * 128 + r) * 256 + k0 + og * 8, &Bs[(size_t)c * 8]);
    }
    __syncthreads();
    short8 af[2], bfr[4];
    #pragma unroll
    for (int i = 0; i < 2; ++i) {
      int ra = w1 * 32 + i * 16 + col;
      af[i] = *(const short8*)&As[(size_t)(ra * 4 + (quad ^ (ra & 3))) * 8];
    }
    #pragma unroll
    for (int j = 0; j < 4; ++j) {
      int rb = w2 * 64 + j * 16 + col;
      bfr[j] = *(const short8*)&Bs[(size_t)(rb * 4 + (quad ^ (rb & 3))) * 8];
    }
    #pragma unroll
    for (int i = 0; i < 2; ++i)
      #pragma unroll
      for (int j = 0; j < 4; ++j)
        acc[i][j] = __builtin_amdgcn_mfma_f32_16x16x32_bf16(af[i], bfr[j], acc[i][j], 0, 0, 0);
    __syncthreads();
  }

  if (mode == 2) {
    // gq = acc+bias (bf16) -> regs+global; c = sig(I)*tanh(G) (c_prev=0); h write
    u16 ga[32];
    #pragma unroll
    for (int i = 0; i < 2; ++i)
      #pragma unroll
      for (int j = 0; j < 4; ++j)
        #pragma unroll
        for (int r = 0; r < 4; ++r)
          ga[(i * 4 + j) * 4 + r] = f2bf(acc[i][j][r] + scv[j]);
    short8* gp = (short8*)(gq_fr + fb * 32);
    #pragma unroll
    for (int t = 0; t < 4; ++t) gp[t] = *(short8*)&ga[t * 8];
    float cnew[8];
    #pragma unroll
    for (int i = 0; i < 2; ++i)
      #pragma unroll
      for (int r = 0; r < 4; ++r) {
        float gI = acc[i][0][r] + scv[0];
        float gG = acc[i][2][r] + scv[2];
        float gO = acc[i][3][r] + scv[3];
        float cn = sigf(gI) * tanh_fast(gG);
        cnew[i * 4 + r] = cn;
        if (u < DM) {
          int m = bm * 64 + w1 * 32 + i * 16 + quad * 4 + r;
          hout[(long)m * DM + u] = f2bf(qev[i * 4 + r] + sigf(gO) * tanh_fast(cn));
        }
      }
    float4* cp = (float4*)(cstate + fb * 8);
    #pragma unroll
    for (int t = 0; t < 2; ++t) cp[t] = *(float4*)&cnew[t * 4];
  } else if (mode == 1) {
    float cnew[8];
    #pragma unroll
    for (int i = 0; i < 2; ++i)
      #pragma unroll
      for (int r = 0; r < 4; ++r) {
        float gI = acc[i][0][r] + scv[0] + bf2f(gqa[(i * 4 + 0) * 4 + r]);
        float gF = acc[i][1][r] + scv[1] + bf2f(gqa[(i * 4 + 1) * 4 + r]);
        float gG = acc[i][2][r] + scv[2] + bf2f(gqa[(i * 4 + 2) * 4 + r]);
        float gO = acc[i][3][r] + scv[3] + bf2f(gqa[(i * 4 + 3) * 4 + r]);
        float cn = sigf(gF) * cpv[i * 4 + r] + sigf(gI) * tanh_fast(gG);
        cnew[i * 4 + r] = cn;
        if (u < DM) {
          int m = bm * 64 + w1 * 32 + i * 16 + quad * 4 + r;
          hout[(long)m * DM + u] = f2bf(qev[i * 4 + r] + sigf(gO) * tanh_fast(cn));
        }
      }
    float4* cp = (float4*)(cstate + fb * 8);
    #pragma unroll
    for (int t = 0; t < 2; ++t) cp[t] = *(float4*)&cnew[t * 4];
  } else {
    // mode 3: c,h dead after; dot with sg, 16-lane reduce, one atomic per row-frag
    #pragma unroll
    for (int i = 0; i < 2; ++i) {
      #pragma unroll
      for (int r = 0; r < 4; ++r) {
        float gI = acc[i][0][r] + scv[0] + bf2f(gqa[(i * 4 + 0) * 4 + r]);
        float gF = acc[i][1][r] + scv[1] + bf2f(gqa[(i * 4 + 1) * 4 + r]);
        float gG = acc[i][2][r] + scv[2] + bf2f(gqa[(i * 4 + 2) * 4 + r]);
        float gO = acc[i][3][r] + scv[3] + bf2f(gqa[(i * 4 + 3) * 4 + r]);
        float cn = sigf(gF) * cpv[i * 4 + r] + sigf(gI) * tanh_fast(gG);
        float hv = qev[i * 4 + r] + sigf(gO) * tanh_fast(cn);
        float p = hv * sgu;
        p += __shfl_xor(p, 1); p += __shfl_xor(p, 2);
        p += __shfl_xor(p, 4); p += __shfl_xor(p, 8);
        if (col == 0) {
          int m = bm * 64 + w1 * 32 + i * 16 + quad * 4 + r;
          atomicAdd(&dotv[m], p);
        }
      }
    }
  }
}

extern "C" void kernel_launch(void* const* d_in, const int* in_sizes, int n_in,
                              void* d_out, int out_size, void* d_ws, size_t ws_size,
                              hipStream_t stream)
{
  const int*   query    = (const int*)  d_in[0];
  const int*   support  = (const int*)  d_in[1];
  const int*   q_l1     = (const int*)  d_in[2];
  const int*   q_deg_l  = (const int*)  d_in[3];
  const int*   q_r1     = (const int*)  d_in[4];
  const int*   q_deg_r  = (const int*)  d_in[5];
  const int*   s_l1     = (const int*)  d_in[6];
  const int*   s_deg_l  = (const int*)  d_in[7];
  const int*   s_r1     = (const int*)  d_in[8];
  const int*   s_deg_r  = (const int*)  d_in[9];
  const float* symbol_emb = (const float*)d_in[10];
  const float* gcn_w_w  = (const float*)d_in[11];
  const float* gcn_w_b  = (const float*)d_in[12];
  const float* gcn_b    = (const float*)d_in[13];
  const float* g1_w     = (const float*)d_in[14];
  const float* g1_b     = (const float*)d_in[15];
  const float* ln1_g    = (const float*)d_in[16];
  const float* ln1_b    = (const float*)d_in[17];
  const float* g2_w     = (const float*)d_in[18];
  const float* g2_b     = (const float*)d_in[19];
  const float* gate_temp= (const float*)d_in[20];
  const float* se_p1_w  = (const float*)d_in[21];
  const float* se_p1_b  = (const float*)d_in[22];
  const float* se_p2_w  = (const float*)d_in[23];
  const float* se_p2_b  = (const float*)d_in[24];
  const float* se_ln_g  = (const float*)d_in[25];
  const float* se_ln_b  = (const float*)d_in[26];
  const float* w_ih     = (const float*)d_in[27];
  const float* w_hh     = (const float*)d_in[28];
  const float* b_ih     = (const float*)d_in[29];
  const float* b_hh     = (const float*)d_in[30];

  float* ws = (float*)d_ws;
  size_t off = 0;
  float* projF   = ws + off; off += (size_t)MROWS * 128 / 2;      // bf16 proj
  float* idxF    = ws + off; off += (size_t)MROWS * 2;
  float* qv      = ws + off; off += (size_t)MQ * DM;
  float* qe      = ws + off; off += (size_t)MQ * DM;
  float* qv_bfF  = ws + off; off += (size_t)MQ * DM / 2;
  float* qe_bfF  = ws + off; off += (size_t)MQ * DM / 2;
  float* h1bF    = ws + off; off += (size_t)MQ * DI / 2;
  float* H2      = ws + off; off += (size_t)MQ * DM;
  float* gqbF    = ws + off; off += (size_t)BQ * NG / 2;          // fragment-order gates (bf16)
  float* cstate  = ws + off; off += (size_t)BQ * LH;              // fragment-order c (fp32)
  float* hbf0F   = ws + off; off += (size_t)BQ * DM / 2;
  float* hbf1F   = ws + off; off += (size_t)BQ * DM / 2;
  float* p1bF    = ws + off; off += 131072 / 2;
  float* p2bF    = ws + off; off += 131072 / 2;
  float* gcnbF   = ws + off; off += 32768 / 2;
  float* wihbF   = ws + off; off += 524288 / 2;
  float* whhbF   = ws + off; off += 524288 / 2;
  float* bihh    = ws + off; off += 2048;
  float* sg      = ws + off; off += 256;
  float* s_corr  = ws + off; off += 2048;
  float* metaF   = ws + off; off += 8448;
  float* embbF   = ws + off; off += (size_t)EMB_ELEMS / 2;        // bf16 symbol table (51 MB)

  u16* proj   = (u16*)projF;
  int* idxA   = (int*)idxF;
  u16* qv_bf  = (u16*)qv_bfF;
  u16* qe_bf  = (u16*)qe_bfF;
  u16* H1_bf  = (u16*)h1bF;
  u16* gq_fr  = (u16*)gqbF;
  u16* hbf0   = (u16*)hbf0F;
  u16* hbf1   = (u16*)hbf1F;
  u16* p1b    = (u16*)p1bF;
  u16* p2b    = (u16*)p2bF;
  u16* gcnb   = (u16*)gcnbF;
  u16* wihb   = (u16*)wihbF;
  u16* whhb   = (u16*)whhbF;
  int* meta   = (int*)metaF;
  u16* embb   = (u16*)embbF;

  // 0. all casts/permutes + bf16 symbol table + d_out zero (one launch)
  {
    long total = (long)NEMB8 + 1345536 + BQ;
    int blocks = (int)((total + 255) / 256);
    prep_all<<<blocks, 256, 0, stream>>>(symbol_emb, embb,
        se_p1_w, se_p2_w, gcn_w_w, w_ih, w_hh, b_ih, b_hh,
        p1b, p2b, gcnb, wihb, whhb, bihh, (float*)d_out);
  }

  // 1. bf16 gather + sims + fused rank/select -> idxA/meta
  nbr_simrank_kernel<<<NBTOT, 256, 0, stream>>>(
      query, support, q_l1, q_r1, s_l1, s_r1, embb, idxA, meta);

  // 2. proj = emb_bf16[idx] @ gcn_w^T  -- 64-row tiles (1282 blocks, 5/CU)
  proj_gather_gemm<<<MROWS / 64, 256, 0, stream>>>(idxA, embb, gcnb, proj);

  // 3. leaky/sum + gate MLP + tanh -> qv rows 0..4100 (query + support)
  nbr_post_kernel<<<NBTOT, 128, 0, stream>>>(
      query, support, q_deg_l, q_deg_r, s_deg_l, s_deg_r, symbol_emb,
      proj, meta, gcn_w_b, gcn_b, g1_w, g1_b, ln1_g, ln1_b, g2_w, g2_b, gate_temp,
      qv, qv_bf);

  // 4. encoder (query + 5 support rows ride along) -- 64x64 tiles for occupancy
  gemm64<<<(MQ / 64) * (DI / 64), 256, 0, stream>>>(qv_bf, 256, p1b, 256, DI, 256,
      nullptr, H1_bf, se_p1_b, 1);
  gemm64<<<(MQ / 64) * (DM / 64), 256, 0, stream>>>(H1_bf, 512, p2b, 512, DM, 512,
      H2, nullptr, se_p2_b, 0);
  ln_residual_kernel<<<BQ + F_SUP, 256, 0, stream>>>(H2, qv, se_ln_g, se_ln_b, qe, qe_bf);

  // 5. LSTM step 1 (mode 2): 64x16=1024 tile blocks + 512 scorr-rider blocks (4/CU)
  lstm_step64<<<1024 + 512, 256, 0, stream>>>(qe_bf, wihb, bihh, gq_fr, cstate, qe,
      hbf0, 2, nullptr, nullptr, w_hh, sg, s_corr);

  // 6. steps 2..3 (mode 1): 1024 blocks each, h ping-pong
  lstm_step64<<<1024, 256, 0, stream>>>(hbf0, whhb, s_corr, gq_fr, cstate, qe,
      hbf1, 1, nullptr, nullptr, nullptr, nullptr, nullptr);
  lstm_step64<<<1024, 256, 0, stream>>>(hbf1, whhb, s_corr, gq_fr, cstate, qe,
      hbf0, 1, nullptr, nullptr, nullptr, nullptr, nullptr);

  // 7. step 4 + fused final dot (mode 3): 512 blocks, u<256 only, no c/h stores
  lstm_step64<<<512, 256, 0, stream>>>(hbf0, whhb, s_corr, gq_fr, cstate, qe,
      nullptr, 3, sg, (float*)d_out, nullptr, nullptr, nullptr);
}